// Round 15
// baseline (168.180 us; speedup 1.0000x reference)
//
#include <hip/hip_runtime.h>
#include <math.h>

#define NND 1024
#define NPTS 2048
#define R_MAX 12.0f
#define DELTA_     (R_MAX / (NPTS - 1))
#define INV_DELTA_ ((NPTS - 1) / R_MAX)

#define STEP_     (5.0f/9.0f)
#define INV_STEP_ 1.8f
#define SQ3_      1.73205080756887729f
#define INV_SQ3_  0.57735026918962576f
#define INV_NN_   0.03126527053f      /* 1/sqrt(1023) */
#define INV_S8_   0.35355339059327373f
#define INV_S32_  0.17677669529663687f
#define LOG2E_    1.44269504088896341f

typedef float f32x4 __attribute__((ext_vector_type(4)));

__device__ __forceinline__ float fast_rcp(float x){ return __builtin_amdgcn_rcpf(x); }
__device__ __forceinline__ float silu_f(float t){
    return t * fast_rcp(1.0f + __builtin_amdgcn_exp2f(t * (-LOG2E_)));
}
__device__ __forceinline__ float sigm_f(float t){
    return fast_rcp(1.0f + __builtin_amdgcn_exp2f(t * (-LOG2E_)));
}

// ---------------- Kernel T: radial tables. T(r)[u] = (silu(emb@W1) @ W2) * 0.1
// (sqrt(10) emb factor cancels the /sqrt(10); 0.1 = 1/sqrt(100) folded in.)
// T[NPTS-1] (r=12) is EXACTLY 0: emb underflows to 0 -> silu(0)=0 -> w=0.
// 4 lanes per point split the j-loop; quad shfl_xor reduce.
__global__ __launch_bounds__(256) void k_tab(
    const float* __restrict__ fc1_w1, const float* __restrict__ fc1_w2,
    const float* __restrict__ fc2_w1, const float* __restrict__ fc2_w2,
    float* __restrict__ tab1, float* __restrict__ tab2)
{
    const int b = blockIdx.x;          // 0..31 -> tab2 (64-wide), 32..63 -> tab1 (16-wide)
    const bool big = (b < 32);
    const int gid = (big ? b : b - 32) * 256 + threadIdx.x;
    const int p = gid >> 2, qj = gid & 3;
    float r = (float)p * DELTA_;
    float emb[10];
#pragma unroll
    for (int k = 0; k < 10; k++){
        float d = (r - (float)k * STEP_) * INV_STEP_;
        emb[k] = __builtin_amdgcn_exp2f((d*d) * (-LOG2E_));
    }
    if (big){
        float w[64];
#pragma unroll
        for (int u = 0; u < 64; u++) w[u] = 0.f;
        for (int j = qj*25; j < qj*25 + 25; j++){
            float t = 0.f;
#pragma unroll
            for (int k = 0; k < 10; k++) t += emb[k] * fc2_w1[k*100 + j];
            float h = silu_f(t);
            const float* wr = &fc2_w2[j*64];
#pragma unroll
            for (int c = 0; c < 16; c++){
                f32x4 wv = *(const f32x4*)(wr + c*4);
#pragma unroll
                for (int e = 0; e < 4; e++) w[c*4+e] += h * wv[e];
            }
        }
#pragma unroll
        for (int u = 0; u < 64; u++){
            w[u] += __shfl_xor(w[u], 1);
            w[u] += __shfl_xor(w[u], 2);
        }
#pragma unroll
        for (int u = 0; u < 16; u++)
            tab2[p*64 + qj*16 + u] = w[qj*16 + u] * 0.1f;
    } else {
        float w[16];
#pragma unroll
        for (int u = 0; u < 16; u++) w[u] = 0.f;
        for (int j = qj*25; j < qj*25 + 25; j++){
            float t = 0.f;
#pragma unroll
            for (int k = 0; k < 10; k++) t += emb[k] * fc1_w1[k*100 + j];
            float h = silu_f(t);
            const float* wr = &fc1_w2[j*16];
#pragma unroll
            for (int c = 0; c < 4; c++){
                f32x4 wv = *(const f32x4*)(wr + c*4);
#pragma unroll
                for (int e = 0; e < 4; e++) w[c*4+e] += h * wv[e];
            }
        }
#pragma unroll
        for (int u = 0; u < 16; u++){
            w[u] += __shfl_xor(w[u], 1);
            w[u] += __shfl_xor(w[u], 2);
        }
#pragma unroll
        for (int u = 0; u < 4; u++)
            tab1[p*16 + qj*4 + u] = w[qj*4 + u] * 0.1f;
    }
}

// lerp index: valid edge -> fi = r/delta (clamped); invalid -> last entry (w = 0 exactly)
__device__ __forceinline__ void tab_idx(float r, bool valid, int& i0, float& frac){
    float fi = valid ? r * INV_DELTA_ : (float)(NPTS - 1);
    fi = fminf(fi, (float)(NPTS - 1));
    i0 = (int)fi;
    if (i0 > NPTS - 2) i0 = NPTS - 2;
    frac = fi - (float)i0;
}

// ---------------- Kernel A: node pre-GEMMs
__global__ __launch_bounds__(64) void k_node_pre(
    const float* __restrict__ x, const float* __restrict__ sc1_w,
    const float* __restrict__ lin1a_w, float* __restrict__ sc, float* __restrict__ xl)
{
    int n = blockIdx.x * blockDim.x + threadIdx.x;
    if (n >= NND) return;
    float xi[8];
#pragma unroll
    for (int i = 0; i < 8; i++) xi[i] = x[n*8 + i];
#pragma unroll
    for (int k = 0; k < 32; k++){
        float a = 0.f;
#pragma unroll
        for (int i = 0; i < 8; i++) a += xi[i] * sc1_w[i*32 + k];
        sc[n*32 + k] = a * INV_S8_;
    }
#pragma unroll
    for (int k = 0; k < 8; k++){
        float a = 0.f;
#pragma unroll
        for (int i = 0; i < 8; i++) a += xi[i] * lin1a_w[i*8 + k];
        xl[n*8 + k] = a * INV_S8_;
    }
}

// ---------------- Kernel B: edge pass 1 via table (round-1 verified skeleton,
// r14-verified 2-way split). Thread per src; 2 srcs per thread per half.
__global__ __launch_bounds__(256) void k_edge1_tab(
    const float* __restrict__ pos, const float* __restrict__ xl,
    const float* __restrict__ tab1, float* __restrict__ m0p, float* __restrict__ m1p)
{
    __shared__ float sred[4][32];
    const int tid  = threadIdx.x;
    const int dst  = blockIdx.x >> 1;
    const int half = blockIdx.x & 1;
    const float qx = pos[dst*3+0], qy = pos[dst*3+1], qz = pos[dst*3+2];
    float acc[32];
#pragma unroll
    for (int k = 0; k < 32; k++) acc[k] = 0.f;

#pragma unroll
    for (int it = 0; it < 2; ++it){
        const int src = half*512 + it*256 + tid;
        float dx = pos[src*3+0]-qx, dy = pos[src*3+1]-qy, dz = pos[src*3+2]-qz;
        float r2 = dx*dx + dy*dy + dz*dz;
        bool valid = (src != dst);
        float rinv = valid ? __builtin_amdgcn_rsqf(r2) : 0.f;
        float r    = r2 * rinv;
        float sf = SQ3_ * rinv;
        float y1x = dx*sf, y1y = dy*sf, y1z = dz*sf;
        int i0; float frac;
        tab_idx(r, valid, i0, frac);
        const float* t0 = &tab1[i0*16];
        float w[16];
#pragma unroll
        for (int c = 0; c < 4; c++){
            f32x4 a = *(const f32x4*)(t0 + c*4);
            f32x4 b = *(const f32x4*)(t0 + 16 + c*4);
#pragma unroll
            for (int e = 0; e < 4; e++) w[c*4+e] = a[e] + frac*(b[e] - a[e]);
        }
        f32x4 xa = *(const f32x4*)&xl[src*8];
        f32x4 xb = *(const f32x4*)&xl[src*8+4];
        float xe[8] = {xa[0],xa[1],xa[2],xa[3], xb[0],xb[1],xb[2],xb[3]};
#pragma unroll
        for (int u = 0; u < 8; u++){
            acc[u] += w[u] * xe[u];           // 0.1 folded into table
            float qv = w[8+u] * xe[u];
            acc[8 + u*3 + 0] += qv*y1x;
            acc[8 + u*3 + 1] += qv*y1y;
            acc[8 + u*3 + 2] += qv*y1z;
        }
    }
    // block reduce (round-1 verified)
#pragma unroll
    for (int off = 32; off > 0; off >>= 1){
#pragma unroll
        for (int k = 0; k < 32; k++) acc[k] += __shfl_down(acc[k], off);
    }
    const int wv = tid >> 6, lane = tid & 63;
    if (lane == 0){
#pragma unroll
        for (int k = 0; k < 32; k++) sred[wv][k] = acc[k];
    }
    __syncthreads();
    if (tid < 32){
        float v = (sred[0][tid] + sred[1][tid]) + (sred[2][tid] + sred[3][tid]);
        v *= INV_NN_;                         // no extra 0.1 (in table)
        float* m0o = m0p + half*8192;
        float* m1o = m1p + half*24576;
        if (tid < 8) m0o[dst*8 + tid] = v;
        else         m1o[dst*24 + (tid - 8)] = v;
    }
}

// ---------------- Kernel C: node middle (sums edge1 halves; a0 folded into a1np.w)
__global__ __launch_bounds__(64) void k_node_mid(
    const float* __restrict__ m0p, const float* __restrict__ m1p,
    const float* __restrict__ sc,
    const float* __restrict__ lin2a0, const float* __restrict__ lin2a1,
    const float* __restrict__ alpha1_w, const float* __restrict__ sc2_w,
    const float* __restrict__ lin1b0, const float* __restrict__ lin1b1,
    float* __restrict__ a1np, float* __restrict__ scv)
{
    int n = blockIdx.x * blockDim.x + threadIdx.x;
    if (n >= NND) return;
    float fm0[8];
#pragma unroll
    for (int u = 0; u < 8; u++) fm0[u] = m0p[n*8 + u] + m0p[8192 + n*8 + u];
    float alpha = 0.f;
#pragma unroll
    for (int u = 0; u < 8; u++) alpha += fm0[u] * alpha1_w[u];
    alpha *= INV_S8_;

    float x0[16], gate[16];
#pragma unroll
    for (int k = 0; k < 32; k++){
        float o = 0.f;
#pragma unroll
        for (int u = 0; u < 8; u++) o += fm0[u] * lin2a0[u*32 + k];
        float sv = sc[n*32 + k] + alpha * (o * INV_S8_);
        if (k < 16) x0[k] = silu_f(sv);
        else        gate[k - 16] = sigm_f(sv);
    }
    float fm1[8][3];
#pragma unroll
    for (int u = 0; u < 8; u++)
#pragma unroll
        for (int c = 0; c < 3; c++)
            fm1[u][c] = m1p[n*24 + u*3 + c] + m1p[24576 + n*24 + u*3 + c];

    float x1[16][3];
#pragma unroll
    for (int v = 0; v < 16; v++){
        float o0 = 0.f, o1 = 0.f, o2 = 0.f;
#pragma unroll
        for (int u = 0; u < 8; u++){
            float wv = lin2a1[u*16 + v];
            o0 += fm1[u][0] * wv; o1 += fm1[u][1] * wv; o2 += fm1[u][2] * wv;
        }
        x1[v][0] = o0 * INV_S8_ * gate[v];
        x1[v][1] = o1 * INV_S8_ * gate[v];
        x1[v][2] = o2 * INV_S8_ * gate[v];
    }
    float s0 = 0.f, s1 = 0.f, s2 = 0.f;
#pragma unroll
    for (int u = 0; u < 16; u++){
        float wv = sc2_w[u];
        s0 += x1[u][0]*wv; s1 += x1[u][1]*wv; s2 += x1[u][2]*wv;
    }
    scv[n*3+0] = s0 * 0.25f; scv[n*3+1] = s1 * 0.25f; scv[n*3+2] = s2 * 0.25f;
#pragma unroll
    for (int v = 0; v < 16; v++){
        float a = 0.f;
#pragma unroll
        for (int u = 0; u < 16; u++) a += x0[u] * lin1b0[u*16 + v];
        float b0 = 0.f, b1 = 0.f, b2 = 0.f;
#pragma unroll
        for (int u = 0; u < 16; u++){
            float wv = lin1b1[u*16 + v];
            b0 += x1[u][0]*wv; b1 += x1[u][1]*wv; b2 += x1[u][2]*wv;
        }
        a1np[n*64 + v*4 + 0] = b0 * 0.25f;
        a1np[n*64 + v*4 + 1] = b1 * 0.25f;
        a1np[n*64 + v*4 + 2] = b2 * 0.25f;
        a1np[n*64 + v*4 + 3] = a  * 0.25f;   // a0 in .w
    }
}

// ---------------- Kernel D: edge pass 2 via table (round-1 verified quad skeleton,
// 2-way split with partial n0/n1). Quad of lanes per edge; lane q owns u = 4q..4q+3.
__global__ __launch_bounds__(256) void k_edge2_tab(
    const float* __restrict__ pos, const float* __restrict__ a1np,
    const float* __restrict__ tab2, float* __restrict__ n0p, float* __restrict__ n1p)
{
    __shared__ float sred[4][4][32];
    const int tid  = threadIdx.x;
    const int q    = tid & 3;
    const int slot = tid >> 2;
    const int dst  = blockIdx.x >> 1;
    const int half = blockIdx.x & 1;
    const float qx = pos[dst*3+0], qy = pos[dst*3+1], qz = pos[dst*3+2];

    float acc[4][8];
#pragma unroll
    for (int a = 0; a < 4; a++)
#pragma unroll
        for (int b = 0; b < 8; b++) acc[a][b] = 0.f;

#pragma unroll 2
    for (int it = 0; it < 8; ++it){
        const int src = half*512 + it*64 + slot;
        float dx = pos[src*3+0]-qx, dy = pos[src*3+1]-qy, dz = pos[src*3+2]-qz;
        float r2 = dx*dx + dy*dy + dz*dz;
        bool valid = (src != dst);
        float rinv = valid ? __builtin_amdgcn_rsqf(r2) : 0.f;
        float r    = r2 * rinv;
        float sf = SQ3_ * rinv;
        float y1x = dx*sf, y1y = dy*sf, y1z = dz*sf;
        int i0; float frac;
        tab_idx(r, valid, i0, frac);
        const float* t0 = &tab2[i0*64 + q*4];
        f32x4 a0v, b0v, a1v, b1v, a2v, b2v, a3v, b3v;
        a0v = *(const f32x4*)(t0     ); b0v = *(const f32x4*)(t0 + 64);
        a1v = *(const f32x4*)(t0 + 16); b1v = *(const f32x4*)(t0 + 80);
        a2v = *(const f32x4*)(t0 + 32); b2v = *(const f32x4*)(t0 + 96);
        a3v = *(const f32x4*)(t0 + 48); b3v = *(const f32x4*)(t0 +112);
        float wa[4], wb[4], wc[4], wd[4];
#pragma unroll
        for (int e = 0; e < 4; e++){
            wa[e] = a0v[e] + frac*(b0v[e] - a0v[e]);
            wb[e] = a1v[e] + frac*(b1v[e] - a1v[e]);
            wc[e] = a2v[e] + frac*(b2v[e] - a2v[e]);
            wd[e] = a3v[e] + frac*(b3v[e] - a3v[e]);
        }
        f32x4 av0 = *(const f32x4*)&a1np[src*64 + (q*4+0)*4];
        f32x4 av1 = *(const f32x4*)&a1np[src*64 + (q*4+1)*4];
        f32x4 av2 = *(const f32x4*)&a1np[src*64 + (q*4+2)*4];
        f32x4 av3 = *(const f32x4*)&a1np[src*64 + (q*4+3)*4];
#define EPI(uu, av) { \
        float A = wa[uu], B = wb[uu], C = wc[uu], D = wd[uu]; \
        acc[uu][0] += A * av[3]; \
        float dv = av[0]*y1x + av[1]*y1y + av[2]*y1z; \
        acc[uu][1] += D * dv * INV_SQ3_; \
        float t2 = B * av[3]; \
        acc[uu][2] += t2*y1x; acc[uu][3] += t2*y1y; acc[uu][4] += t2*y1z; \
        acc[uu][5] += C*av[0]; acc[uu][6] += C*av[1]; acc[uu][7] += C*av[2]; }
        EPI(0, av0) EPI(1, av1) EPI(2, av2) EPI(3, av3)
#undef EPI
    }
    // reduce the 16 slots within each wave (lanes with equal q combine) — round-1 verified
#pragma unroll
    for (int off = 4; off <= 32; off <<= 1)
#pragma unroll
        for (int a = 0; a < 4; a++)
#pragma unroll
            for (int b = 0; b < 8; b++) acc[a][b] += __shfl_xor(acc[a][b], off);
    const int wv = tid >> 6, lane = tid & 63;
    if (lane < 4){
#pragma unroll
        for (int a = 0; a < 4; a++)
#pragma unroll
            for (int b = 0; b < 8; b++) sred[wv][lane][a*8 + b] = acc[a][b];
    }
    __syncthreads();
    if (tid < 128){
        int q2 = tid >> 5, k = tid & 31;
        float v = (sred[0][q2][k] + sred[1][q2][k]) + (sred[2][q2][k] + sred[3][q2][k]);
        v *= INV_NN_;                         // 0.1 in table; INV_SQ3 already inline
        int uu = k >> 3, cp = k & 7;
        int u = q2*4 + uu;
        float* n0o = n0p + half*32768;
        float* n1o = n1p + half*98304;
        if      (cp == 0) n0o[dst*32 + u] = v;
        else if (cp == 1) n0o[dst*32 + 16 + u] = v;
        else if (cp < 5)  n1o[dst*96 + u*3 + (cp-2)] = v;
        else              n1o[dst*96 + (16+u)*3 + (cp-5)] = v;
    }
}

// ---------------- Kernel E1: final per-node combine (sums edge2 halves)
__global__ __launch_bounds__(64) void k_final_part(
    const float* __restrict__ n0p, const float* __restrict__ n1p,
    const float* __restrict__ scv, const float* __restrict__ lin2b,
    const float* __restrict__ alpha2_w, float* __restrict__ fpart)
{
    const int n = blockIdx.x * 64 + threadIdx.x;
    float ov0 = 0.f, ov1 = 0.f, ov2 = 0.f, al = 0.f;
#pragma unroll
    for (int u = 0; u < 32; u++){
        float w = lin2b[u];
        ov0 += (n1p[n*96 + u*3 + 0] + n1p[98304 + n*96 + u*3 + 0]) * w;
        ov1 += (n1p[n*96 + u*3 + 1] + n1p[98304 + n*96 + u*3 + 1]) * w;
        ov2 += (n1p[n*96 + u*3 + 2] + n1p[98304 + n*96 + u*3 + 2]) * w;
        al  += (n0p[n*32 + u] + n0p[32768 + n*32 + u]) * alpha2_w[u];
    }
    al *= INV_S32_;
    float acc0 = scv[n*3+0] + al * ov0 * INV_S32_;
    float acc1 = scv[n*3+1] + al * ov1 * INV_S32_;
    float acc2 = scv[n*3+2] + al * ov2 * INV_S32_;
#pragma unroll
    for (int off = 32; off > 0; off >>= 1){
        acc0 += __shfl_down(acc0, off);
        acc1 += __shfl_down(acc1, off);
        acc2 += __shfl_down(acc2, off);
    }
    if (threadIdx.x == 0){
        fpart[blockIdx.x*3 + 0] = acc0;
        fpart[blockIdx.x*3 + 1] = acc1;
        fpart[blockIdx.x*3 + 2] = acc2;
    }
}

// ---------------- Kernel E2: finish
__global__ __launch_bounds__(64) void k_final2(
    const float* __restrict__ fpart, float* __restrict__ out)
{
    const int l = threadIdx.x;
    float v0 = (l < 16) ? fpart[l*3 + 0] : 0.f;
    float v1 = (l < 16) ? fpart[l*3 + 1] : 0.f;
    float v2 = (l < 16) ? fpart[l*3 + 2] : 0.f;
#pragma unroll
    for (int off = 8; off > 0; off >>= 1){
        v0 += __shfl_down(v0, off);
        v1 += __shfl_down(v1, off);
        v2 += __shfl_down(v2, off);
    }
    if (l == 0){
        out[0] = v0 * (1.0f/32.0f);   // 1/sqrt(1024)
        out[1] = v1 * (1.0f/32.0f);
        out[2] = v2 * (1.0f/32.0f);
    }
}

extern "C" void kernel_launch(void* const* d_in, const int* in_sizes, int n_in,
                              void* d_out, int out_size, void* d_ws, size_t ws_size,
                              hipStream_t stream)
{
    const float* pos      = (const float*)d_in[0];
    const float* x        = (const float*)d_in[1];
    // d_in[2], d_in[3]: edge_src/edge_dst — dense all-pairs graph, enumerated directly
    const float* sc1_w    = (const float*)d_in[4];
    const float* lin1a_w  = (const float*)d_in[5];
    const float* fc1_w1   = (const float*)d_in[6];
    const float* fc1_w2   = (const float*)d_in[7];
    const float* lin2a0   = (const float*)d_in[8];
    const float* lin2a1   = (const float*)d_in[9];
    const float* alpha1_w = (const float*)d_in[10];
    const float* sc2_w    = (const float*)d_in[11];
    const float* lin1b0   = (const float*)d_in[12];
    const float* lin1b1   = (const float*)d_in[13];
    const float* fc2_w1   = (const float*)d_in[14];
    const float* fc2_w2   = (const float*)d_in[15];
    const float* lin2b    = (const float*)d_in[16];
    const float* alpha2_w = (const float*)d_in[17];

    float* ws    = (float*)d_ws;
    float* sc    = ws;               // 32768
    float* xl    = sc    + 32768;    // 8192
    float* m0p   = xl    + 8192;     // 2 x 8192
    float* m1p   = m0p   + 16384;    // 2 x 24576
    float* a1np  = m1p   + 49152;    // 65536
    float* scv   = a1np  + 65536;    // 3072
    float* n1p   = scv   + 3072;     // 2 x 98304
    float* fpart = n1p   + 196608;   // 48
    float* tab1  = fpart + 48;       // 2048*16 = 32768
    float* tab2  = tab1  + 32768;    // 2048*64 = 131072
    float* n0p   = m0p;              // alias m0p+m1p (65536 floats), dead after node_mid

    k_tab<<<64, 256, 0, stream>>>(fc1_w1, fc1_w2, fc2_w1, fc2_w2, tab1, tab2);
    k_node_pre<<<16, 64, 0, stream>>>(x, sc1_w, lin1a_w, sc, xl);
    k_edge1_tab<<<2*NND, 256, 0, stream>>>(pos, xl, tab1, m0p, m1p);
    k_node_mid<<<16, 64, 0, stream>>>(m0p, m1p, sc, lin2a0, lin2a1, alpha1_w, sc2_w,
                                      lin1b0, lin1b1, a1np, scv);
    k_edge2_tab<<<2*NND, 256, 0, stream>>>(pos, a1np, tab2, n0p, n1p);
    k_final_part<<<16, 64, 0, stream>>>(n0p, n1p, scv, lin2b, alpha2_w, fpart);
    k_final2<<<1, 64, 0, stream>>>(fpart, (float*)d_out);
}

// Round 16
// 139.855 us; speedup vs baseline: 1.2025x; 1.2025x over previous
//
#include <hip/hip_runtime.h>
#include <math.h>

#define NND 1024
#define NPTS 2048
#define R_MAX 12.0f
#define DELTA_     (R_MAX / (NPTS - 1))
#define INV_DELTA_ ((NPTS - 1) / R_MAX)

#define STEP_     (5.0f/9.0f)
#define INV_STEP_ 1.8f
#define SQ3_      1.73205080756887729f
#define INV_SQ3_  0.57735026918962576f
#define INV_NN_   0.03126527053f      /* 1/sqrt(1023) */
#define INV_S8_   0.35355339059327373f
#define INV_S32_  0.17677669529663687f
#define LOG2E_    1.44269504088896341f

typedef float f32x4 __attribute__((ext_vector_type(4)));

__device__ __forceinline__ float fast_rcp(float x){ return __builtin_amdgcn_rcpf(x); }
__device__ __forceinline__ float silu_f(float t){
    return t * fast_rcp(1.0f + __builtin_amdgcn_exp2f(t * (-LOG2E_)));
}
__device__ __forceinline__ float sigm_f(float t){
    return fast_rcp(1.0f + __builtin_amdgcn_exp2f(t * (-LOG2E_)));
}

// ---------------- Kernel T: radial tables. T(r)[u] = (silu(emb@W1) @ W2) * 0.1
// (sqrt(10) emb factor cancels /sqrt(10); 0.1 = 1/sqrt(100) folded in.)
// T[NPTS-1] (r=12) is EXACTLY 0 (emb underflows). One thread per (point,
// 16-wide output slice) — ALL register indices static (round-15 bug: runtime
// qj-indexed w[64] spilled to scratch -> 65 µs, 900MB HBM).
__global__ __launch_bounds__(256) void k_tab(
    const float* __restrict__ fc1_w1, const float* __restrict__ fc1_w2,
    const float* __restrict__ fc2_w1, const float* __restrict__ fc2_w2,
    float* __restrict__ tab1, float* __restrict__ tab2)
{
    const int b = blockIdx.x;
    const bool big = (b < 32);                 // 0..31: tab2 slices; 32..39: tab1
    const int gid = (big ? b : b - 32) * 256 + threadIdx.x;
    const int p  = big ? (gid >> 2) : gid;
    const int cg = big ? (gid & 3) : 0;
    const float r = (float)p * DELTA_;
    float emb[10];
#pragma unroll
    for (int k = 0; k < 10; k++){
        float d = (r - (float)k * STEP_) * INV_STEP_;
        emb[k] = __builtin_amdgcn_exp2f((d*d) * (-LOG2E_));
    }
    const float* W1 = big ? fc2_w1 : fc1_w1;
    const float* W2 = big ? (fc2_w2 + cg*16) : fc1_w2;
    const int    ld = big ? 64 : 16;
    float w[16];
#pragma unroll
    for (int u = 0; u < 16; u++) w[u] = 0.f;
    for (int j = 0; j < 100; j++){
        float t = 0.f;
#pragma unroll
        for (int k = 0; k < 10; k++) t += emb[k] * W1[k*100 + j];
        float h = silu_f(t);
        const float* wr = W2 + j*ld;
#pragma unroll
        for (int c = 0; c < 4; c++){
            f32x4 wv = *(const f32x4*)(wr + c*4);
#pragma unroll
            for (int e = 0; e < 4; e++) w[c*4+e] += h * wv[e];
        }
    }
    float* outp = big ? (tab2 + p*64 + cg*16) : (tab1 + p*16);
#pragma unroll
    for (int u = 0; u < 16; u++) outp[u] = w[u] * 0.1f;
}

// lerp index: valid edge -> fi = r/delta (clamped); invalid -> last entry (w = 0 exactly)
__device__ __forceinline__ void tab_idx(float r, bool valid, int& i0, float& frac){
    float fi = valid ? r * INV_DELTA_ : (float)(NPTS - 1);
    fi = fminf(fi, (float)(NPTS - 1));
    i0 = (int)fi;
    if (i0 > NPTS - 2) i0 = NPTS - 2;
    frac = fi - (float)i0;
}

// ---------------- Kernel A: node pre-GEMMs
__global__ __launch_bounds__(64) void k_node_pre(
    const float* __restrict__ x, const float* __restrict__ sc1_w,
    const float* __restrict__ lin1a_w, float* __restrict__ sc, float* __restrict__ xl)
{
    int n = blockIdx.x * blockDim.x + threadIdx.x;
    if (n >= NND) return;
    float xi[8];
#pragma unroll
    for (int i = 0; i < 8; i++) xi[i] = x[n*8 + i];
#pragma unroll
    for (int k = 0; k < 32; k++){
        float a = 0.f;
#pragma unroll
        for (int i = 0; i < 8; i++) a += xi[i] * sc1_w[i*32 + k];
        sc[n*32 + k] = a * INV_S8_;
    }
#pragma unroll
    for (int k = 0; k < 8; k++){
        float a = 0.f;
#pragma unroll
        for (int i = 0; i < 8; i++) a += xi[i] * lin1a_w[i*8 + k];
        xl[n*8 + k] = a * INV_S8_;
    }
}

// ---------------- Kernel B: edge pass 1 via table (r15-verified)
__global__ __launch_bounds__(256) void k_edge1_tab(
    const float* __restrict__ pos, const float* __restrict__ xl,
    const float* __restrict__ tab1, float* __restrict__ m0p, float* __restrict__ m1p)
{
    __shared__ float sred[4][32];
    const int tid  = threadIdx.x;
    const int dst  = blockIdx.x >> 1;
    const int half = blockIdx.x & 1;
    const float qx = pos[dst*3+0], qy = pos[dst*3+1], qz = pos[dst*3+2];
    float acc[32];
#pragma unroll
    for (int k = 0; k < 32; k++) acc[k] = 0.f;

#pragma unroll
    for (int it = 0; it < 2; ++it){
        const int src = half*512 + it*256 + tid;
        float dx = pos[src*3+0]-qx, dy = pos[src*3+1]-qy, dz = pos[src*3+2]-qz;
        float r2 = dx*dx + dy*dy + dz*dz;
        bool valid = (src != dst);
        float rinv = valid ? __builtin_amdgcn_rsqf(r2) : 0.f;
        float r    = r2 * rinv;
        float sf = SQ3_ * rinv;
        float y1x = dx*sf, y1y = dy*sf, y1z = dz*sf;
        int i0; float frac;
        tab_idx(r, valid, i0, frac);
        const float* t0 = &tab1[i0*16];
        float w[16];
#pragma unroll
        for (int c = 0; c < 4; c++){
            f32x4 a = *(const f32x4*)(t0 + c*4);
            f32x4 b = *(const f32x4*)(t0 + 16 + c*4);
#pragma unroll
            for (int e = 0; e < 4; e++) w[c*4+e] = a[e] + frac*(b[e] - a[e]);
        }
        f32x4 xa = *(const f32x4*)&xl[src*8];
        f32x4 xb = *(const f32x4*)&xl[src*8+4];
        float xe[8] = {xa[0],xa[1],xa[2],xa[3], xb[0],xb[1],xb[2],xb[3]};
#pragma unroll
        for (int u = 0; u < 8; u++){
            acc[u] += w[u] * xe[u];           // 0.1 folded into table
            float qv = w[8+u] * xe[u];
            acc[8 + u*3 + 0] += qv*y1x;
            acc[8 + u*3 + 1] += qv*y1y;
            acc[8 + u*3 + 2] += qv*y1z;
        }
    }
    // block reduce
#pragma unroll
    for (int off = 32; off > 0; off >>= 1){
#pragma unroll
        for (int k = 0; k < 32; k++) acc[k] += __shfl_down(acc[k], off);
    }
    const int wv = tid >> 6, lane = tid & 63;
    if (lane == 0){
#pragma unroll
        for (int k = 0; k < 32; k++) sred[wv][k] = acc[k];
    }
    __syncthreads();
    if (tid < 32){
        float v = (sred[0][tid] + sred[1][tid]) + (sred[2][tid] + sred[3][tid]);
        v *= INV_NN_;
        float* m0o = m0p + half*8192;
        float* m1o = m1p + half*24576;
        if (tid < 8) m0o[dst*8 + tid] = v;
        else         m1o[dst*24 + (tid - 8)] = v;
    }
}

// ---------------- Kernel C: node middle (sums edge1 halves; a0 folded into a1np.w)
__global__ __launch_bounds__(64) void k_node_mid(
    const float* __restrict__ m0p, const float* __restrict__ m1p,
    const float* __restrict__ sc,
    const float* __restrict__ lin2a0, const float* __restrict__ lin2a1,
    const float* __restrict__ alpha1_w, const float* __restrict__ sc2_w,
    const float* __restrict__ lin1b0, const float* __restrict__ lin1b1,
    float* __restrict__ a1np, float* __restrict__ scv)
{
    int n = blockIdx.x * blockDim.x + threadIdx.x;
    if (n >= NND) return;
    float fm0[8];
#pragma unroll
    for (int u = 0; u < 8; u++) fm0[u] = m0p[n*8 + u] + m0p[8192 + n*8 + u];
    float alpha = 0.f;
#pragma unroll
    for (int u = 0; u < 8; u++) alpha += fm0[u] * alpha1_w[u];
    alpha *= INV_S8_;

    float x0[16], gate[16];
#pragma unroll
    for (int k = 0; k < 32; k++){
        float o = 0.f;
#pragma unroll
        for (int u = 0; u < 8; u++) o += fm0[u] * lin2a0[u*32 + k];
        float sv = sc[n*32 + k] + alpha * (o * INV_S8_);
        if (k < 16) x0[k] = silu_f(sv);
        else        gate[k - 16] = sigm_f(sv);
    }
    float fm1[8][3];
#pragma unroll
    for (int u = 0; u < 8; u++)
#pragma unroll
        for (int c = 0; c < 3; c++)
            fm1[u][c] = m1p[n*24 + u*3 + c] + m1p[24576 + n*24 + u*3 + c];

    float x1[16][3];
#pragma unroll
    for (int v = 0; v < 16; v++){
        float o0 = 0.f, o1 = 0.f, o2 = 0.f;
#pragma unroll
        for (int u = 0; u < 8; u++){
            float wv = lin2a1[u*16 + v];
            o0 += fm1[u][0] * wv; o1 += fm1[u][1] * wv; o2 += fm1[u][2] * wv;
        }
        x1[v][0] = o0 * INV_S8_ * gate[v];
        x1[v][1] = o1 * INV_S8_ * gate[v];
        x1[v][2] = o2 * INV_S8_ * gate[v];
    }
    float s0 = 0.f, s1 = 0.f, s2 = 0.f;
#pragma unroll
    for (int u = 0; u < 16; u++){
        float wv = sc2_w[u];
        s0 += x1[u][0]*wv; s1 += x1[u][1]*wv; s2 += x1[u][2]*wv;
    }
    scv[n*3+0] = s0 * 0.25f; scv[n*3+1] = s1 * 0.25f; scv[n*3+2] = s2 * 0.25f;
#pragma unroll
    for (int v = 0; v < 16; v++){
        float a = 0.f;
#pragma unroll
        for (int u = 0; u < 16; u++) a += x0[u] * lin1b0[u*16 + v];
        float b0 = 0.f, b1 = 0.f, b2 = 0.f;
#pragma unroll
        for (int u = 0; u < 16; u++){
            float wv = lin1b1[u*16 + v];
            b0 += x1[u][0]*wv; b1 += x1[u][1]*wv; b2 += x1[u][2]*wv;
        }
        a1np[n*64 + v*4 + 0] = b0 * 0.25f;
        a1np[n*64 + v*4 + 1] = b1 * 0.25f;
        a1np[n*64 + v*4 + 2] = b2 * 0.25f;
        a1np[n*64 + v*4 + 3] = a  * 0.25f;   // a0 in .w
    }
}

// ---------------- Kernel D: edge pass 2 via table (r15-verified quad skeleton)
__global__ __launch_bounds__(256) void k_edge2_tab(
    const float* __restrict__ pos, const float* __restrict__ a1np,
    const float* __restrict__ tab2, float* __restrict__ n0p, float* __restrict__ n1p)
{
    __shared__ float sred[4][4][32];
    const int tid  = threadIdx.x;
    const int q    = tid & 3;
    const int slot = tid >> 2;
    const int dst  = blockIdx.x >> 1;
    const int half = blockIdx.x & 1;
    const float qx = pos[dst*3+0], qy = pos[dst*3+1], qz = pos[dst*3+2];

    float acc[4][8];
#pragma unroll
    for (int a = 0; a < 4; a++)
#pragma unroll
        for (int b = 0; b < 8; b++) acc[a][b] = 0.f;

#pragma unroll 2
    for (int it = 0; it < 8; ++it){
        const int src = half*512 + it*64 + slot;
        float dx = pos[src*3+0]-qx, dy = pos[src*3+1]-qy, dz = pos[src*3+2]-qz;
        float r2 = dx*dx + dy*dy + dz*dz;
        bool valid = (src != dst);
        float rinv = valid ? __builtin_amdgcn_rsqf(r2) : 0.f;
        float r    = r2 * rinv;
        float sf = SQ3_ * rinv;
        float y1x = dx*sf, y1y = dy*sf, y1z = dz*sf;
        int i0; float frac;
        tab_idx(r, valid, i0, frac);
        const float* t0 = &tab2[i0*64 + q*4];
        f32x4 a0v, b0v, a1v, b1v, a2v, b2v, a3v, b3v;
        a0v = *(const f32x4*)(t0     ); b0v = *(const f32x4*)(t0 + 64);
        a1v = *(const f32x4*)(t0 + 16); b1v = *(const f32x4*)(t0 + 80);
        a2v = *(const f32x4*)(t0 + 32); b2v = *(const f32x4*)(t0 + 96);
        a3v = *(const f32x4*)(t0 + 48); b3v = *(const f32x4*)(t0 +112);
        float wa[4], wb[4], wc[4], wd[4];
#pragma unroll
        for (int e = 0; e < 4; e++){
            wa[e] = a0v[e] + frac*(b0v[e] - a0v[e]);
            wb[e] = a1v[e] + frac*(b1v[e] - a1v[e]);
            wc[e] = a2v[e] + frac*(b2v[e] - a2v[e]);
            wd[e] = a3v[e] + frac*(b3v[e] - a3v[e]);
        }
        f32x4 av0 = *(const f32x4*)&a1np[src*64 + (q*4+0)*4];
        f32x4 av1 = *(const f32x4*)&a1np[src*64 + (q*4+1)*4];
        f32x4 av2 = *(const f32x4*)&a1np[src*64 + (q*4+2)*4];
        f32x4 av3 = *(const f32x4*)&a1np[src*64 + (q*4+3)*4];
#define EPI(uu, av) { \
        float A = wa[uu], B = wb[uu], C = wc[uu], D = wd[uu]; \
        acc[uu][0] += A * av[3]; \
        float dv = av[0]*y1x + av[1]*y1y + av[2]*y1z; \
        acc[uu][1] += D * dv * INV_SQ3_; \
        float t2 = B * av[3]; \
        acc[uu][2] += t2*y1x; acc[uu][3] += t2*y1y; acc[uu][4] += t2*y1z; \
        acc[uu][5] += C*av[0]; acc[uu][6] += C*av[1]; acc[uu][7] += C*av[2]; }
        EPI(0, av0) EPI(1, av1) EPI(2, av2) EPI(3, av3)
#undef EPI
    }
    // reduce the 16 slots within each wave (lanes with equal q combine)
#pragma unroll
    for (int off = 4; off <= 32; off <<= 1)
#pragma unroll
        for (int a = 0; a < 4; a++)
#pragma unroll
            for (int b = 0; b < 8; b++) acc[a][b] += __shfl_xor(acc[a][b], off);
    const int wv = tid >> 6, lane = tid & 63;
    if (lane < 4){
#pragma unroll
        for (int a = 0; a < 4; a++)
#pragma unroll
            for (int b = 0; b < 8; b++) sred[wv][lane][a*8 + b] = acc[a][b];
    }
    __syncthreads();
    if (tid < 128){
        int q2 = tid >> 5, k = tid & 31;
        float v = (sred[0][q2][k] + sred[1][q2][k]) + (sred[2][q2][k] + sred[3][q2][k]);
        v *= INV_NN_;
        int uu = k >> 3, cp = k & 7;
        int u = q2*4 + uu;
        float* n0o = n0p + half*32768;
        float* n1o = n1p + half*98304;
        if      (cp == 0) n0o[dst*32 + u] = v;
        else if (cp == 1) n0o[dst*32 + 16 + u] = v;
        else if (cp < 5)  n1o[dst*96 + u*3 + (cp-2)] = v;
        else              n1o[dst*96 + (16+u)*3 + (cp-5)] = v;
    }
}

// ---------------- Kernel E1: final per-node combine (sums edge2 halves)
__global__ __launch_bounds__(64) void k_final_part(
    const float* __restrict__ n0p, const float* __restrict__ n1p,
    const float* __restrict__ scv, const float* __restrict__ lin2b,
    const float* __restrict__ alpha2_w, float* __restrict__ fpart)
{
    const int n = blockIdx.x * 64 + threadIdx.x;
    float ov0 = 0.f, ov1 = 0.f, ov2 = 0.f, al = 0.f;
#pragma unroll
    for (int u = 0; u < 32; u++){
        float w = lin2b[u];
        ov0 += (n1p[n*96 + u*3 + 0] + n1p[98304 + n*96 + u*3 + 0]) * w;
        ov1 += (n1p[n*96 + u*3 + 1] + n1p[98304 + n*96 + u*3 + 1]) * w;
        ov2 += (n1p[n*96 + u*3 + 2] + n1p[98304 + n*96 + u*3 + 2]) * w;
        al  += (n0p[n*32 + u] + n0p[32768 + n*32 + u]) * alpha2_w[u];
    }
    al *= INV_S32_;
    float acc0 = scv[n*3+0] + al * ov0 * INV_S32_;
    float acc1 = scv[n*3+1] + al * ov1 * INV_S32_;
    float acc2 = scv[n*3+2] + al * ov2 * INV_S32_;
#pragma unroll
    for (int off = 32; off > 0; off >>= 1){
        acc0 += __shfl_down(acc0, off);
        acc1 += __shfl_down(acc1, off);
        acc2 += __shfl_down(acc2, off);
    }
    if (threadIdx.x == 0){
        fpart[blockIdx.x*3 + 0] = acc0;
        fpart[blockIdx.x*3 + 1] = acc1;
        fpart[blockIdx.x*3 + 2] = acc2;
    }
}

// ---------------- Kernel E2: finish
__global__ __launch_bounds__(64) void k_final2(
    const float* __restrict__ fpart, float* __restrict__ out)
{
    const int l = threadIdx.x;
    float v0 = (l < 16) ? fpart[l*3 + 0] : 0.f;
    float v1 = (l < 16) ? fpart[l*3 + 1] : 0.f;
    float v2 = (l < 16) ? fpart[l*3 + 2] : 0.f;
#pragma unroll
    for (int off = 8; off > 0; off >>= 1){
        v0 += __shfl_down(v0, off);
        v1 += __shfl_down(v1, off);
        v2 += __shfl_down(v2, off);
    }
    if (l == 0){
        out[0] = v0 * (1.0f/32.0f);   // 1/sqrt(1024)
        out[1] = v1 * (1.0f/32.0f);
        out[2] = v2 * (1.0f/32.0f);
    }
}

extern "C" void kernel_launch(void* const* d_in, const int* in_sizes, int n_in,
                              void* d_out, int out_size, void* d_ws, size_t ws_size,
                              hipStream_t stream)
{
    const float* pos      = (const float*)d_in[0];
    const float* x        = (const float*)d_in[1];
    // d_in[2], d_in[3]: edge_src/edge_dst — dense all-pairs graph, enumerated directly
    const float* sc1_w    = (const float*)d_in[4];
    const float* lin1a_w  = (const float*)d_in[5];
    const float* fc1_w1   = (const float*)d_in[6];
    const float* fc1_w2   = (const float*)d_in[7];
    const float* lin2a0   = (const float*)d_in[8];
    const float* lin2a1   = (const float*)d_in[9];
    const float* alpha1_w = (const float*)d_in[10];
    const float* sc2_w    = (const float*)d_in[11];
    const float* lin1b0   = (const float*)d_in[12];
    const float* lin1b1   = (const float*)d_in[13];
    const float* fc2_w1   = (const float*)d_in[14];
    const float* fc2_w2   = (const float*)d_in[15];
    const float* lin2b    = (const float*)d_in[16];
    const float* alpha2_w = (const float*)d_in[17];

    float* ws    = (float*)d_ws;
    float* sc    = ws;               // 32768
    float* xl    = sc    + 32768;    // 8192
    float* m0p   = xl    + 8192;     // 2 x 8192
    float* m1p   = m0p   + 16384;    // 2 x 24576
    float* a1np  = m1p   + 49152;    // 65536
    float* scv   = a1np  + 65536;    // 3072
    float* n1p   = scv   + 3072;     // 2 x 98304
    float* fpart = n1p   + 196608;   // 48
    float* tab1  = fpart + 48;       // 2048*16 = 32768
    float* tab2  = tab1  + 32768;    // 2048*64 = 131072
    float* n0p   = m0p;              // alias m0p+m1p (65536 floats), dead after node_mid

    k_tab<<<40, 256, 0, stream>>>(fc1_w1, fc1_w2, fc2_w1, fc2_w2, tab1, tab2);
    k_node_pre<<<16, 64, 0, stream>>>(x, sc1_w, lin1a_w, sc, xl);
    k_edge1_tab<<<2*NND, 256, 0, stream>>>(pos, xl, tab1, m0p, m1p);
    k_node_mid<<<16, 64, 0, stream>>>(m0p, m1p, sc, lin2a0, lin2a1, alpha1_w, sc2_w,
                                      lin1b0, lin1b1, a1np, scv);
    k_edge2_tab<<<2*NND, 256, 0, stream>>>(pos, a1np, tab2, n0p, n1p);
    k_final_part<<<16, 64, 0, stream>>>(n0p, n1p, scv, lin2b, alpha2_w, fpart);
    k_final2<<<1, 64, 0, stream>>>(fpart, (float*)d_out);
}

// Round 17
// 107.899 us; speedup vs baseline: 1.5587x; 1.2962x over previous
//
#include <hip/hip_runtime.h>
#include <math.h>

#define NND 1024
#define NPTS 2048
#define R_MAX 12.0f
#define DELTA_     (R_MAX / (NPTS - 1))
#define INV_DELTA_ ((NPTS - 1) / R_MAX)

#define STEP_     (5.0f/9.0f)
#define INV_STEP_ 1.8f
#define SQ3_      1.73205080756887729f
#define INV_SQ3_  0.57735026918962576f
#define INV_NN_   0.03126527053f      /* 1/sqrt(1023) */
#define INV_S8_   0.35355339059327373f
#define INV_S32_  0.17677669529663687f
#define LOG2E_    1.44269504088896341f

typedef float f32x4 __attribute__((ext_vector_type(4)));

__device__ __forceinline__ float fast_rcp(float x){ return __builtin_amdgcn_rcpf(x); }
__device__ __forceinline__ float silu_f(float t){
    return t * fast_rcp(1.0f + __builtin_amdgcn_exp2f(t * (-LOG2E_)));
}
__device__ __forceinline__ float sigm_f(float t){
    return fast_rcp(1.0f + __builtin_amdgcn_exp2f(t * (-LOG2E_)));
}

// ---------------- Kernel T: radial tables (r16-verified). T[last] = exactly 0.
__global__ __launch_bounds__(256) void k_tab(
    const float* __restrict__ fc1_w1, const float* __restrict__ fc1_w2,
    const float* __restrict__ fc2_w1, const float* __restrict__ fc2_w2,
    float* __restrict__ tab1, float* __restrict__ tab2)
{
    const int b = blockIdx.x;
    const bool big = (b < 32);                 // 0..31: tab2 slices; 32..39: tab1
    const int gid = (big ? b : b - 32) * 256 + threadIdx.x;
    const int p  = big ? (gid >> 2) : gid;
    const int cg = big ? (gid & 3) : 0;
    const float r = (float)p * DELTA_;
    float emb[10];
#pragma unroll
    for (int k = 0; k < 10; k++){
        float d = (r - (float)k * STEP_) * INV_STEP_;
        emb[k] = __builtin_amdgcn_exp2f((d*d) * (-LOG2E_));
    }
    const float* W1 = big ? fc2_w1 : fc1_w1;
    const float* W2 = big ? (fc2_w2 + cg*16) : fc1_w2;
    const int    ld = big ? 64 : 16;
    float w[16];
#pragma unroll
    for (int u = 0; u < 16; u++) w[u] = 0.f;
    for (int j = 0; j < 100; j++){
        float t = 0.f;
#pragma unroll
        for (int k = 0; k < 10; k++) t += emb[k] * W1[k*100 + j];
        float h = silu_f(t);
        const float* wr = W2 + j*ld;
#pragma unroll
        for (int c = 0; c < 4; c++){
            f32x4 wv = *(const f32x4*)(wr + c*4);
#pragma unroll
            for (int e = 0; e < 4; e++) w[c*4+e] += h * wv[e];
        }
    }
    float* outp = big ? (tab2 + p*64 + cg*16) : (tab1 + p*16);
#pragma unroll
    for (int u = 0; u < 16; u++) outp[u] = w[u] * 0.1f;
}

// lerp index: valid -> fi = r/delta (clamped); invalid -> last entry (w = 0 exactly)
__device__ __forceinline__ void tab_idx(float r, bool valid, int& i0, float& frac){
    float fi = valid ? r * INV_DELTA_ : (float)(NPTS - 1);
    fi = fminf(fi, (float)(NPTS - 1));
    i0 = (int)fi;
    if (i0 > NPTS - 2) i0 = NPTS - 2;
    frac = fi - (float)i0;
}

// ---------------- Kernel A: node pre-GEMMs. thread = (n, q); q-th 8-slice of sc,
// q==0 also does xl. 4096 threads (was 1024 @ 0.15% occupancy).
__global__ __launch_bounds__(256) void k_node_pre(
    const float* __restrict__ x, const float* __restrict__ sc1_w,
    const float* __restrict__ lin1a_w, float* __restrict__ sc, float* __restrict__ xl)
{
    const int gid = blockIdx.x * 256 + threadIdx.x;
    const int n = gid >> 2, q = gid & 3;
    float xi[8];
#pragma unroll
    for (int i = 0; i < 8; i++) xi[i] = x[n*8 + i];
#pragma unroll
    for (int kk = 0; kk < 8; kk++){
        int k = q*8 + kk;
        float a = 0.f;
#pragma unroll
        for (int i = 0; i < 8; i++) a += xi[i] * sc1_w[i*32 + k];
        sc[n*32 + k] = a * INV_S8_;
    }
    if (q == 0){
#pragma unroll
        for (int k = 0; k < 8; k++){
            float a = 0.f;
#pragma unroll
            for (int i = 0; i < 8; i++) a += xi[i] * lin1a_w[i*8 + k];
            xl[n*8 + k] = a * INV_S8_;
        }
    }
}

// ---------------- Kernel B: edge pass 1 via table (r16-verified)
__global__ __launch_bounds__(256) void k_edge1_tab(
    const float* __restrict__ pos, const float* __restrict__ xl,
    const float* __restrict__ tab1, float* __restrict__ m0p, float* __restrict__ m1p)
{
    __shared__ float sred[4][32];
    const int tid  = threadIdx.x;
    const int dst  = blockIdx.x >> 1;
    const int half = blockIdx.x & 1;
    const float qx = pos[dst*3+0], qy = pos[dst*3+1], qz = pos[dst*3+2];
    float acc[32];
#pragma unroll
    for (int k = 0; k < 32; k++) acc[k] = 0.f;

#pragma unroll
    for (int it = 0; it < 2; ++it){
        const int src = half*512 + it*256 + tid;
        float dx = pos[src*3+0]-qx, dy = pos[src*3+1]-qy, dz = pos[src*3+2]-qz;
        float r2 = dx*dx + dy*dy + dz*dz;
        bool valid = (src != dst);
        float rinv = valid ? __builtin_amdgcn_rsqf(r2) : 0.f;
        float r    = r2 * rinv;
        float sf = SQ3_ * rinv;
        float y1x = dx*sf, y1y = dy*sf, y1z = dz*sf;
        int i0; float frac;
        tab_idx(r, valid, i0, frac);
        const float* t0 = &tab1[i0*16];
        float w[16];
#pragma unroll
        for (int c = 0; c < 4; c++){
            f32x4 a = *(const f32x4*)(t0 + c*4);
            f32x4 b = *(const f32x4*)(t0 + 16 + c*4);
#pragma unroll
            for (int e = 0; e < 4; e++) w[c*4+e] = a[e] + frac*(b[e] - a[e]);
        }
        f32x4 xa = *(const f32x4*)&xl[src*8];
        f32x4 xb = *(const f32x4*)&xl[src*8+4];
        float xe[8] = {xa[0],xa[1],xa[2],xa[3], xb[0],xb[1],xb[2],xb[3]};
#pragma unroll
        for (int u = 0; u < 8; u++){
            acc[u] += w[u] * xe[u];           // 0.1 folded into table
            float qv = w[8+u] * xe[u];
            acc[8 + u*3 + 0] += qv*y1x;
            acc[8 + u*3 + 1] += qv*y1y;
            acc[8 + u*3 + 2] += qv*y1z;
        }
    }
#pragma unroll
    for (int off = 32; off > 0; off >>= 1){
#pragma unroll
        for (int k = 0; k < 32; k++) acc[k] += __shfl_down(acc[k], off);
    }
    const int wv = tid >> 6, lane = tid & 63;
    if (lane == 0){
#pragma unroll
        for (int k = 0; k < 32; k++) sred[wv][k] = acc[k];
    }
    __syncthreads();
    if (tid < 32){
        float v = (sred[0][tid] + sred[1][tid]) + (sred[2][tid] + sred[3][tid]);
        v *= INV_NN_;
        float* m0o = m0p + half*8192;
        float* m1o = m1p + half*24576;
        if (tid < 8) m0o[dst*8 + tid] = v;
        else         m1o[dst*24 + (tid - 8)] = v;
    }
}

// ---------------- Kernel C: node middle. thread = (n, vo); vo-column of a1np.
// Shared state (x0/gate/x1) recomputed redundantly per thread (cheap); all
// register indices static. 16384 threads (was 1024 @ 0.15% occupancy, 55 µs).
__global__ __launch_bounds__(256) void k_node_mid(
    const float* __restrict__ m0p, const float* __restrict__ m1p,
    const float* __restrict__ sc,
    const float* __restrict__ lin2a0, const float* __restrict__ lin2a1,
    const float* __restrict__ alpha1_w, const float* __restrict__ sc2_w,
    const float* __restrict__ lin1b0, const float* __restrict__ lin1b1,
    float* __restrict__ a1np, float* __restrict__ scv)
{
    const int gid = blockIdx.x * 256 + threadIdx.x;   // 64 blocks
    const int n  = gid >> 4;
    const int vo = gid & 15;
    float fm0[8];
#pragma unroll
    for (int u = 0; u < 8; u++) fm0[u] = m0p[n*8 + u] + m0p[8192 + n*8 + u];
    float alpha = 0.f;
#pragma unroll
    for (int u = 0; u < 8; u++) alpha += fm0[u] * alpha1_w[u];
    alpha *= INV_S8_;

    float x0[16], gate[16];
#pragma unroll
    for (int k = 0; k < 32; k++){
        float o = 0.f;
#pragma unroll
        for (int u = 0; u < 8; u++) o += fm0[u] * lin2a0[u*32 + k];
        float sv = sc[n*32 + k] + alpha * (o * INV_S8_);
        if (k < 16) x0[k] = silu_f(sv);
        else        gate[k - 16] = sigm_f(sv);
    }
    float fm1[8][3];
#pragma unroll
    for (int u = 0; u < 8; u++)
#pragma unroll
        for (int c = 0; c < 3; c++)
            fm1[u][c] = m1p[n*24 + u*3 + c] + m1p[24576 + n*24 + u*3 + c];

    float x1[16][3];
#pragma unroll
    for (int v = 0; v < 16; v++){
        float o0 = 0.f, o1 = 0.f, o2 = 0.f;
#pragma unroll
        for (int u = 0; u < 8; u++){
            float wv = lin2a1[u*16 + v];
            o0 += fm1[u][0] * wv; o1 += fm1[u][1] * wv; o2 += fm1[u][2] * wv;
        }
        x1[v][0] = o0 * INV_S8_ * gate[v];
        x1[v][1] = o1 * INV_S8_ * gate[v];
        x1[v][2] = o2 * INV_S8_ * gate[v];
    }
    // vo-specific outputs
    float a = 0.f, b0 = 0.f, b1 = 0.f, b2 = 0.f;
#pragma unroll
    for (int u = 0; u < 16; u++){
        a += x0[u] * lin1b0[u*16 + vo];
        float wv = lin1b1[u*16 + vo];
        b0 += x1[u][0]*wv; b1 += x1[u][1]*wv; b2 += x1[u][2]*wv;
    }
    a1np[n*64 + vo*4 + 0] = b0 * 0.25f;
    a1np[n*64 + vo*4 + 1] = b1 * 0.25f;
    a1np[n*64 + vo*4 + 2] = b2 * 0.25f;
    a1np[n*64 + vo*4 + 3] = a  * 0.25f;   // a0 in .w
    if (vo == 0){
        float s0 = 0.f, s1 = 0.f, s2 = 0.f;
#pragma unroll
        for (int u = 0; u < 16; u++){
            float wv = sc2_w[u];
            s0 += x1[u][0]*wv; s1 += x1[u][1]*wv; s2 += x1[u][2]*wv;
        }
        scv[n*3+0] = s0 * 0.25f; scv[n*3+1] = s1 * 0.25f; scv[n*3+2] = s2 * 0.25f;
    }
}

// ---------------- Kernel D: edge pass 2 via table (r16-verified quad skeleton)
__global__ __launch_bounds__(256) void k_edge2_tab(
    const float* __restrict__ pos, const float* __restrict__ a1np,
    const float* __restrict__ tab2, float* __restrict__ n0p, float* __restrict__ n1p)
{
    __shared__ float sred[4][4][32];
    const int tid  = threadIdx.x;
    const int q    = tid & 3;
    const int slot = tid >> 2;
    const int dst  = blockIdx.x >> 1;
    const int half = blockIdx.x & 1;
    const float qx = pos[dst*3+0], qy = pos[dst*3+1], qz = pos[dst*3+2];

    float acc[4][8];
#pragma unroll
    for (int a = 0; a < 4; a++)
#pragma unroll
        for (int b = 0; b < 8; b++) acc[a][b] = 0.f;

#pragma unroll 2
    for (int it = 0; it < 8; ++it){
        const int src = half*512 + it*64 + slot;
        float dx = pos[src*3+0]-qx, dy = pos[src*3+1]-qy, dz = pos[src*3+2]-qz;
        float r2 = dx*dx + dy*dy + dz*dz;
        bool valid = (src != dst);
        float rinv = valid ? __builtin_amdgcn_rsqf(r2) : 0.f;
        float r    = r2 * rinv;
        float sf = SQ3_ * rinv;
        float y1x = dx*sf, y1y = dy*sf, y1z = dz*sf;
        int i0; float frac;
        tab_idx(r, valid, i0, frac);
        const float* t0 = &tab2[i0*64 + q*4];
        f32x4 a0v, b0v, a1v, b1v, a2v, b2v, a3v, b3v;
        a0v = *(const f32x4*)(t0     ); b0v = *(const f32x4*)(t0 + 64);
        a1v = *(const f32x4*)(t0 + 16); b1v = *(const f32x4*)(t0 + 80);
        a2v = *(const f32x4*)(t0 + 32); b2v = *(const f32x4*)(t0 + 96);
        a3v = *(const f32x4*)(t0 + 48); b3v = *(const f32x4*)(t0 +112);
        float wa[4], wb[4], wc[4], wd[4];
#pragma unroll
        for (int e = 0; e < 4; e++){
            wa[e] = a0v[e] + frac*(b0v[e] - a0v[e]);
            wb[e] = a1v[e] + frac*(b1v[e] - a1v[e]);
            wc[e] = a2v[e] + frac*(b2v[e] - a2v[e]);
            wd[e] = a3v[e] + frac*(b3v[e] - a3v[e]);
        }
        f32x4 av0 = *(const f32x4*)&a1np[src*64 + (q*4+0)*4];
        f32x4 av1 = *(const f32x4*)&a1np[src*64 + (q*4+1)*4];
        f32x4 av2 = *(const f32x4*)&a1np[src*64 + (q*4+2)*4];
        f32x4 av3 = *(const f32x4*)&a1np[src*64 + (q*4+3)*4];
#define EPI(uu, av) { \
        float A = wa[uu], B = wb[uu], C = wc[uu], D = wd[uu]; \
        acc[uu][0] += A * av[3]; \
        float dv = av[0]*y1x + av[1]*y1y + av[2]*y1z; \
        acc[uu][1] += D * dv * INV_SQ3_; \
        float t2 = B * av[3]; \
        acc[uu][2] += t2*y1x; acc[uu][3] += t2*y1y; acc[uu][4] += t2*y1z; \
        acc[uu][5] += C*av[0]; acc[uu][6] += C*av[1]; acc[uu][7] += C*av[2]; }
        EPI(0, av0) EPI(1, av1) EPI(2, av2) EPI(3, av3)
#undef EPI
    }
#pragma unroll
    for (int off = 4; off <= 32; off <<= 1)
#pragma unroll
        for (int a = 0; a < 4; a++)
#pragma unroll
            for (int b = 0; b < 8; b++) acc[a][b] += __shfl_xor(acc[a][b], off);
    const int wv = tid >> 6, lane = tid & 63;
    if (lane < 4){
#pragma unroll
        for (int a = 0; a < 4; a++)
#pragma unroll
            for (int b = 0; b < 8; b++) sred[wv][lane][a*8 + b] = acc[a][b];
    }
    __syncthreads();
    if (tid < 128){
        int q2 = tid >> 5, k = tid & 31;
        float v = (sred[0][q2][k] + sred[1][q2][k]) + (sred[2][q2][k] + sred[3][q2][k]);
        v *= INV_NN_;
        int uu = k >> 3, cp = k & 7;
        int u = q2*4 + uu;
        float* n0o = n0p + half*32768;
        float* n1o = n1p + half*98304;
        if      (cp == 0) n0o[dst*32 + u] = v;
        else if (cp == 1) n0o[dst*32 + 16 + u] = v;
        else if (cp < 5)  n1o[dst*96 + u*3 + (cp-2)] = v;
        else              n1o[dst*96 + (16+u)*3 + (cp-5)] = v;
    }
}

// ---------------- Kernel E1: final per-node combine. thread = (n, q):
// q = hsel*2 + uhalf; quad shfl_xor merges al/ov BEFORE the nonlinear al*ov.
__global__ __launch_bounds__(256) void k_final_part(
    const float* __restrict__ n0p, const float* __restrict__ n1p,
    const float* __restrict__ scv, const float* __restrict__ lin2b,
    const float* __restrict__ alpha2_w, float* __restrict__ fpart)
{
    __shared__ float sred[4][3];
    const int tid = threadIdx.x;
    const int gid = blockIdx.x * 256 + tid;   // 16 blocks x 256
    const int n = gid >> 2;
    const int q = gid & 3;
    const int hsel = q >> 1, uh = (q & 1) << 4;
    const float* n0b = n0p + hsel*32768;
    const float* n1b = n1p + hsel*98304;
    float ov0 = 0.f, ov1 = 0.f, ov2 = 0.f, al = 0.f;
#pragma unroll
    for (int uu = 0; uu < 16; uu++){
        int u = uh + uu;
        float w = lin2b[u];
        ov0 += n1b[n*96 + u*3 + 0] * w;
        ov1 += n1b[n*96 + u*3 + 1] * w;
        ov2 += n1b[n*96 + u*3 + 2] * w;
        al  += n0b[n*32 + u] * alpha2_w[u];
    }
    ov0 += __shfl_xor(ov0, 1); ov0 += __shfl_xor(ov0, 2);
    ov1 += __shfl_xor(ov1, 1); ov1 += __shfl_xor(ov1, 2);
    ov2 += __shfl_xor(ov2, 1); ov2 += __shfl_xor(ov2, 2);
    al  += __shfl_xor(al , 1); al  += __shfl_xor(al , 2);
    float acc0 = 0.f, acc1 = 0.f, acc2 = 0.f;
    if (q == 0){
        al *= INV_S32_;
        acc0 = scv[n*3+0] + al * ov0 * INV_S32_;
        acc1 = scv[n*3+1] + al * ov1 * INV_S32_;
        acc2 = scv[n*3+2] + al * ov2 * INV_S32_;
    }
#pragma unroll
    for (int off = 32; off > 0; off >>= 1){
        acc0 += __shfl_down(acc0, off);
        acc1 += __shfl_down(acc1, off);
        acc2 += __shfl_down(acc2, off);
    }
    const int wv = tid >> 6, lane = tid & 63;
    if (lane == 0){ sred[wv][0] = acc0; sred[wv][1] = acc1; sred[wv][2] = acc2; }
    __syncthreads();
    if (tid == 0){
        fpart[blockIdx.x*3 + 0] = sred[0][0] + sred[1][0] + sred[2][0] + sred[3][0];
        fpart[blockIdx.x*3 + 1] = sred[0][1] + sred[1][1] + sred[2][1] + sred[3][1];
        fpart[blockIdx.x*3 + 2] = sred[0][2] + sred[1][2] + sred[2][2] + sred[3][2];
    }
}

// ---------------- Kernel E2: finish
__global__ __launch_bounds__(64) void k_final2(
    const float* __restrict__ fpart, float* __restrict__ out)
{
    const int l = threadIdx.x;
    float v0 = (l < 16) ? fpart[l*3 + 0] : 0.f;
    float v1 = (l < 16) ? fpart[l*3 + 1] : 0.f;
    float v2 = (l < 16) ? fpart[l*3 + 2] : 0.f;
#pragma unroll
    for (int off = 8; off > 0; off >>= 1){
        v0 += __shfl_down(v0, off);
        v1 += __shfl_down(v1, off);
        v2 += __shfl_down(v2, off);
    }
    if (l == 0){
        out[0] = v0 * (1.0f/32.0f);   // 1/sqrt(1024)
        out[1] = v1 * (1.0f/32.0f);
        out[2] = v2 * (1.0f/32.0f);
    }
}

extern "C" void kernel_launch(void* const* d_in, const int* in_sizes, int n_in,
                              void* d_out, int out_size, void* d_ws, size_t ws_size,
                              hipStream_t stream)
{
    const float* pos      = (const float*)d_in[0];
    const float* x        = (const float*)d_in[1];
    // d_in[2], d_in[3]: edge_src/edge_dst — dense all-pairs graph, enumerated directly
    const float* sc1_w    = (const float*)d_in[4];
    const float* lin1a_w  = (const float*)d_in[5];
    const float* fc1_w1   = (const float*)d_in[6];
    const float* fc1_w2   = (const float*)d_in[7];
    const float* lin2a0   = (const float*)d_in[8];
    const float* lin2a1   = (const float*)d_in[9];
    const float* alpha1_w = (const float*)d_in[10];
    const float* sc2_w    = (const float*)d_in[11];
    const float* lin1b0   = (const float*)d_in[12];
    const float* lin1b1   = (const float*)d_in[13];
    const float* fc2_w1   = (const float*)d_in[14];
    const float* fc2_w2   = (const float*)d_in[15];
    const float* lin2b    = (const float*)d_in[16];
    const float* alpha2_w = (const float*)d_in[17];

    float* ws    = (float*)d_ws;
    float* sc    = ws;               // 32768
    float* xl    = sc    + 32768;    // 8192
    float* m0p   = xl    + 8192;     // 2 x 8192
    float* m1p   = m0p   + 16384;    // 2 x 24576
    float* a1np  = m1p   + 49152;    // 65536
    float* scv   = a1np  + 65536;    // 3072
    float* n1p   = scv   + 3072;     // 2 x 98304
    float* fpart = n1p   + 196608;   // 48
    float* tab1  = fpart + 48;       // 2048*16 = 32768
    float* tab2  = tab1  + 32768;    // 2048*64 = 131072
    float* n0p   = m0p;              // alias m0p+m1p (65536 floats), dead after node_mid

    k_tab<<<40, 256, 0, stream>>>(fc1_w1, fc1_w2, fc2_w1, fc2_w2, tab1, tab2);
    k_node_pre<<<16, 256, 0, stream>>>(x, sc1_w, lin1a_w, sc, xl);
    k_edge1_tab<<<2*NND, 256, 0, stream>>>(pos, xl, tab1, m0p, m1p);
    k_node_mid<<<64, 256, 0, stream>>>(m0p, m1p, sc, lin2a0, lin2a1, alpha1_w, sc2_w,
                                       lin1b0, lin1b1, a1np, scv);
    k_edge2_tab<<<2*NND, 256, 0, stream>>>(pos, a1np, tab2, n0p, n1p);
    k_final_part<<<16, 256, 0, stream>>>(n0p, n1p, scv, lin2b, alpha2_w, fpart);
    k_final2<<<1, 64, 0, stream>>>(fpart, (float*)d_out);
}

// Round 18
// 90.305 us; speedup vs baseline: 1.8624x; 1.1948x over previous
//
#include <hip/hip_runtime.h>
#include <math.h>

#define NND 1024
#define NPTS 2048
#define R_MAX 12.0f
#define DELTA_     (R_MAX / (NPTS - 1))
#define INV_DELTA_ ((NPTS - 1) / R_MAX)

#define STEP_     (5.0f/9.0f)
#define INV_STEP_ 1.8f
#define SQ3_      1.73205080756887729f
#define INV_SQ3_  0.57735026918962576f
#define INV_NN_   0.03126527053f      /* 1/sqrt(1023) */
#define INV_S8_   0.35355339059327373f
#define INV_S32_  0.17677669529663687f
#define LOG2E_    1.44269504088896341f

typedef float f32x4 __attribute__((ext_vector_type(4)));

__device__ __forceinline__ float fast_rcp(float x){ return __builtin_amdgcn_rcpf(x); }
__device__ __forceinline__ float silu_f(float t){
    return t * fast_rcp(1.0f + __builtin_amdgcn_exp2f(t * (-LOG2E_)));
}
__device__ __forceinline__ float sigm_f(float t){
    return fast_rcp(1.0f + __builtin_amdgcn_exp2f(t * (-LOG2E_)));
}

// ---------------- Kernel T1: H = silu(emb @ W1) for both MLPs, elementwise.
// thread = (point p, hidden j). blocks 0..NPTS-1: MLP2; NPTS..2*NPTS-1: MLP1.
// (r17's k_tab was 50 µs: 40 blocks -> 1 wave/SIMD on 40 CUs, 100-iter
// dependent-load chain unhidden. Flattened: chains ~10 ops, full machine.)
__global__ __launch_bounds__(256) void k_tab_h(
    const float* __restrict__ fc1_w1, const float* __restrict__ fc2_w1,
    float* __restrict__ h1, float* __restrict__ h2)
{
    const int b = blockIdx.x;
    const bool big = (b < NPTS/2*2) && (b < 2048);   // blocks 0..2047 -> MLP2? no:
    // blocks [0, NPTS/128*... ] — use: first half of grid MLP2, second half MLP1.
    const int half = (b >= (NPTS/2));               // NPTS/2 blocks of 256 = NPTS*128
    const int gid = (half ? b - NPTS/2 : b) * 256 + threadIdx.x;
    const int p  = gid >> 7;          // 128 jj-slots per point
    const int jj = gid & 127;
    if (jj >= 100 || p >= NPTS) return;
    const float r = (float)p * DELTA_;
    float emb[10];
#pragma unroll
    for (int k = 0; k < 10; k++){
        float d = (r - (float)k * STEP_) * INV_STEP_;
        emb[k] = __builtin_amdgcn_exp2f((d*d) * (-LOG2E_));
    }
    const float* W1 = half ? fc1_w1 : fc2_w1;
    float t = 0.f;
#pragma unroll
    for (int k = 0; k < 10; k++) t += emb[k] * W1[k*100 + jj];
    float hv = silu_f(t);
    if (half) h1[p*100 + jj] = hv;
    else      h2[p*100 + jj] = hv;
}

// ---------------- Kernel T2: TAB = H @ W2 * 0.1. thread = (p, u).
// blocks 0..511: tab2 (u<64); 512..639: tab1 (u<16). H reads wave-broadcast,
// W2 reads coalesced. T[last] = exactly 0 (emb underflow -> h row of silu(0)).
__global__ __launch_bounds__(256) void k_tab_out(
    const float* __restrict__ h1, const float* __restrict__ h2,
    const float* __restrict__ fc1_w2, const float* __restrict__ fc2_w2,
    float* __restrict__ tab1, float* __restrict__ tab2)
{
    const int b = blockIdx.x;
    if (b < 512){
        const int gid = b*256 + threadIdx.x;
        const int p = gid >> 6, u = gid & 63;
        const float* hp = &h2[p*100];
        float acc = 0.f;
        for (int j = 0; j < 100; j++) acc += hp[j] * fc2_w2[j*64 + u];
        tab2[p*64 + u] = acc * 0.1f;
    } else {
        const int gid = (b - 512)*256 + threadIdx.x;
        const int p = gid >> 4, u = gid & 15;
        const float* hp = &h1[p*100];
        float acc = 0.f;
        for (int j = 0; j < 100; j++) acc += hp[j] * fc1_w2[j*16 + u];
        tab1[p*16 + u] = acc * 0.1f;
    }
}

// lerp index: valid -> fi = r/delta (clamped); invalid -> last entry (w = 0 exactly)
__device__ __forceinline__ void tab_idx(float r, bool valid, int& i0, float& frac){
    float fi = valid ? r * INV_DELTA_ : (float)(NPTS - 1);
    fi = fminf(fi, (float)(NPTS - 1));
    i0 = (int)fi;
    if (i0 > NPTS - 2) i0 = NPTS - 2;
    frac = fi - (float)i0;
}

// ---------------- Kernel A: node pre-GEMMs (r17-verified)
__global__ __launch_bounds__(256) void k_node_pre(
    const float* __restrict__ x, const float* __restrict__ sc1_w,
    const float* __restrict__ lin1a_w, float* __restrict__ sc, float* __restrict__ xl)
{
    const int gid = blockIdx.x * 256 + threadIdx.x;
    const int n = gid >> 2, q = gid & 3;
    float xi[8];
#pragma unroll
    for (int i = 0; i < 8; i++) xi[i] = x[n*8 + i];
#pragma unroll
    for (int kk = 0; kk < 8; kk++){
        int k = q*8 + kk;
        float a = 0.f;
#pragma unroll
        for (int i = 0; i < 8; i++) a += xi[i] * sc1_w[i*32 + k];
        sc[n*32 + k] = a * INV_S8_;
    }
    if (q == 0){
#pragma unroll
        for (int k = 0; k < 8; k++){
            float a = 0.f;
#pragma unroll
            for (int i = 0; i < 8; i++) a += xi[i] * lin1a_w[i*8 + k];
            xl[n*8 + k] = a * INV_S8_;
        }
    }
}

// ---------------- Kernel B: edge pass 1 via table (r17-verified)
__global__ __launch_bounds__(256) void k_edge1_tab(
    const float* __restrict__ pos, const float* __restrict__ xl,
    const float* __restrict__ tab1, float* __restrict__ m0p, float* __restrict__ m1p)
{
    __shared__ float sred[4][32];
    const int tid  = threadIdx.x;
    const int dst  = blockIdx.x >> 1;
    const int half = blockIdx.x & 1;
    const float qx = pos[dst*3+0], qy = pos[dst*3+1], qz = pos[dst*3+2];
    float acc[32];
#pragma unroll
    for (int k = 0; k < 32; k++) acc[k] = 0.f;

#pragma unroll
    for (int it = 0; it < 2; ++it){
        const int src = half*512 + it*256 + tid;
        float dx = pos[src*3+0]-qx, dy = pos[src*3+1]-qy, dz = pos[src*3+2]-qz;
        float r2 = dx*dx + dy*dy + dz*dz;
        bool valid = (src != dst);
        float rinv = valid ? __builtin_amdgcn_rsqf(r2) : 0.f;
        float r    = r2 * rinv;
        float sf = SQ3_ * rinv;
        float y1x = dx*sf, y1y = dy*sf, y1z = dz*sf;
        int i0; float frac;
        tab_idx(r, valid, i0, frac);
        const float* t0 = &tab1[i0*16];
        float w[16];
#pragma unroll
        for (int c = 0; c < 4; c++){
            f32x4 a = *(const f32x4*)(t0 + c*4);
            f32x4 b = *(const f32x4*)(t0 + 16 + c*4);
#pragma unroll
            for (int e = 0; e < 4; e++) w[c*4+e] = a[e] + frac*(b[e] - a[e]);
        }
        f32x4 xa = *(const f32x4*)&xl[src*8];
        f32x4 xb = *(const f32x4*)&xl[src*8+4];
        float xe[8] = {xa[0],xa[1],xa[2],xa[3], xb[0],xb[1],xb[2],xb[3]};
#pragma unroll
        for (int u = 0; u < 8; u++){
            acc[u] += w[u] * xe[u];           // 0.1 folded into table
            float qv = w[8+u] * xe[u];
            acc[8 + u*3 + 0] += qv*y1x;
            acc[8 + u*3 + 1] += qv*y1y;
            acc[8 + u*3 + 2] += qv*y1z;
        }
    }
#pragma unroll
    for (int off = 32; off > 0; off >>= 1){
#pragma unroll
        for (int k = 0; k < 32; k++) acc[k] += __shfl_down(acc[k], off);
    }
    const int wv = tid >> 6, lane = tid & 63;
    if (lane == 0){
#pragma unroll
        for (int k = 0; k < 32; k++) sred[wv][k] = acc[k];
    }
    __syncthreads();
    if (tid < 32){
        float v = (sred[0][tid] + sred[1][tid]) + (sred[2][tid] + sred[3][tid]);
        v *= INV_NN_;
        float* m0o = m0p + half*8192;
        float* m1o = m1p + half*24576;
        if (tid < 8) m0o[dst*8 + tid] = v;
        else         m1o[dst*24 + (tid - 8)] = v;
    }
}

// ---------------- Kernel C: node middle (r17-verified)
__global__ __launch_bounds__(256) void k_node_mid(
    const float* __restrict__ m0p, const float* __restrict__ m1p,
    const float* __restrict__ sc,
    const float* __restrict__ lin2a0, const float* __restrict__ lin2a1,
    const float* __restrict__ alpha1_w, const float* __restrict__ sc2_w,
    const float* __restrict__ lin1b0, const float* __restrict__ lin1b1,
    float* __restrict__ a1np, float* __restrict__ scv)
{
    const int gid = blockIdx.x * 256 + threadIdx.x;   // 64 blocks
    const int n  = gid >> 4;
    const int vo = gid & 15;
    float fm0[8];
#pragma unroll
    for (int u = 0; u < 8; u++) fm0[u] = m0p[n*8 + u] + m0p[8192 + n*8 + u];
    float alpha = 0.f;
#pragma unroll
    for (int u = 0; u < 8; u++) alpha += fm0[u] * alpha1_w[u];
    alpha *= INV_S8_;

    float x0[16], gate[16];
#pragma unroll
    for (int k = 0; k < 32; k++){
        float o = 0.f;
#pragma unroll
        for (int u = 0; u < 8; u++) o += fm0[u] * lin2a0[u*32 + k];
        float sv = sc[n*32 + k] + alpha * (o * INV_S8_);
        if (k < 16) x0[k] = silu_f(sv);
        else        gate[k - 16] = sigm_f(sv);
    }
    float fm1[8][3];
#pragma unroll
    for (int u = 0; u < 8; u++)
#pragma unroll
        for (int c = 0; c < 3; c++)
            fm1[u][c] = m1p[n*24 + u*3 + c] + m1p[24576 + n*24 + u*3 + c];

    float x1[16][3];
#pragma unroll
    for (int v = 0; v < 16; v++){
        float o0 = 0.f, o1 = 0.f, o2 = 0.f;
#pragma unroll
        for (int u = 0; u < 8; u++){
            float wv = lin2a1[u*16 + v];
            o0 += fm1[u][0] * wv; o1 += fm1[u][1] * wv; o2 += fm1[u][2] * wv;
        }
        x1[v][0] = o0 * INV_S8_ * gate[v];
        x1[v][1] = o1 * INV_S8_ * gate[v];
        x1[v][2] = o2 * INV_S8_ * gate[v];
    }
    float a = 0.f, b0 = 0.f, b1 = 0.f, b2 = 0.f;
#pragma unroll
    for (int u = 0; u < 16; u++){
        a += x0[u] * lin1b0[u*16 + vo];
        float wv = lin1b1[u*16 + vo];
        b0 += x1[u][0]*wv; b1 += x1[u][1]*wv; b2 += x1[u][2]*wv;
    }
    a1np[n*64 + vo*4 + 0] = b0 * 0.25f;
    a1np[n*64 + vo*4 + 1] = b1 * 0.25f;
    a1np[n*64 + vo*4 + 2] = b2 * 0.25f;
    a1np[n*64 + vo*4 + 3] = a  * 0.25f;   // a0 in .w
    if (vo == 0){
        float s0 = 0.f, s1 = 0.f, s2 = 0.f;
#pragma unroll
        for (int u = 0; u < 16; u++){
            float wv = sc2_w[u];
            s0 += x1[u][0]*wv; s1 += x1[u][1]*wv; s2 += x1[u][2]*wv;
        }
        scv[n*3+0] = s0 * 0.25f; scv[n*3+1] = s1 * 0.25f; scv[n*3+2] = s2 * 0.25f;
    }
}

// ---------------- Kernel D: edge pass 2 via table (r17-verified)
__global__ __launch_bounds__(256) void k_edge2_tab(
    const float* __restrict__ pos, const float* __restrict__ a1np,
    const float* __restrict__ tab2, float* __restrict__ n0p, float* __restrict__ n1p)
{
    __shared__ float sred[4][4][32];
    const int tid  = threadIdx.x;
    const int q    = tid & 3;
    const int slot = tid >> 2;
    const int dst  = blockIdx.x >> 1;
    const int half = blockIdx.x & 1;
    const float qx = pos[dst*3+0], qy = pos[dst*3+1], qz = pos[dst*3+2];

    float acc[4][8];
#pragma unroll
    for (int a = 0; a < 4; a++)
#pragma unroll
        for (int b = 0; b < 8; b++) acc[a][b] = 0.f;

#pragma unroll 2
    for (int it = 0; it < 8; ++it){
        const int src = half*512 + it*64 + slot;
        float dx = pos[src*3+0]-qx, dy = pos[src*3+1]-qy, dz = pos[src*3+2]-qz;
        float r2 = dx*dx + dy*dy + dz*dz;
        bool valid = (src != dst);
        float rinv = valid ? __builtin_amdgcn_rsqf(r2) : 0.f;
        float r    = r2 * rinv;
        float sf = SQ3_ * rinv;
        float y1x = dx*sf, y1y = dy*sf, y1z = dz*sf;
        int i0; float frac;
        tab_idx(r, valid, i0, frac);
        const float* t0 = &tab2[i0*64 + q*4];
        f32x4 a0v, b0v, a1v, b1v, a2v, b2v, a3v, b3v;
        a0v = *(const f32x4*)(t0     ); b0v = *(const f32x4*)(t0 + 64);
        a1v = *(const f32x4*)(t0 + 16); b1v = *(const f32x4*)(t0 + 80);
        a2v = *(const f32x4*)(t0 + 32); b2v = *(const f32x4*)(t0 + 96);
        a3v = *(const f32x4*)(t0 + 48); b3v = *(const f32x4*)(t0 +112);
        float wa[4], wb[4], wc[4], wd[4];
#pragma unroll
        for (int e = 0; e < 4; e++){
            wa[e] = a0v[e] + frac*(b0v[e] - a0v[e]);
            wb[e] = a1v[e] + frac*(b1v[e] - a1v[e]);
            wc[e] = a2v[e] + frac*(b2v[e] - a2v[e]);
            wd[e] = a3v[e] + frac*(b3v[e] - a3v[e]);
        }
        f32x4 av0 = *(const f32x4*)&a1np[src*64 + (q*4+0)*4];
        f32x4 av1 = *(const f32x4*)&a1np[src*64 + (q*4+1)*4];
        f32x4 av2 = *(const f32x4*)&a1np[src*64 + (q*4+2)*4];
        f32x4 av3 = *(const f32x4*)&a1np[src*64 + (q*4+3)*4];
#define EPI(uu, av) { \
        float A = wa[uu], B = wb[uu], C = wc[uu], D = wd[uu]; \
        acc[uu][0] += A * av[3]; \
        float dv = av[0]*y1x + av[1]*y1y + av[2]*y1z; \
        acc[uu][1] += D * dv * INV_SQ3_; \
        float t2 = B * av[3]; \
        acc[uu][2] += t2*y1x; acc[uu][3] += t2*y1y; acc[uu][4] += t2*y1z; \
        acc[uu][5] += C*av[0]; acc[uu][6] += C*av[1]; acc[uu][7] += C*av[2]; }
        EPI(0, av0) EPI(1, av1) EPI(2, av2) EPI(3, av3)
#undef EPI
    }
#pragma unroll
    for (int off = 4; off <= 32; off <<= 1)
#pragma unroll
        for (int a = 0; a < 4; a++)
#pragma unroll
            for (int b = 0; b < 8; b++) acc[a][b] += __shfl_xor(acc[a][b], off);
    const int wv = tid >> 6, lane = tid & 63;
    if (lane < 4){
#pragma unroll
        for (int a = 0; a < 4; a++)
#pragma unroll
            for (int b = 0; b < 8; b++) sred[wv][lane][a*8 + b] = acc[a][b];
    }
    __syncthreads();
    if (tid < 128){
        int q2 = tid >> 5, k = tid & 31;
        float v = (sred[0][q2][k] + sred[1][q2][k]) + (sred[2][q2][k] + sred[3][q2][k]);
        v *= INV_NN_;
        int uu = k >> 3, cp = k & 7;
        int u = q2*4 + uu;
        float* n0o = n0p + half*32768;
        float* n1o = n1p + half*98304;
        if      (cp == 0) n0o[dst*32 + u] = v;
        else if (cp == 1) n0o[dst*32 + 16 + u] = v;
        else if (cp < 5)  n1o[dst*96 + u*3 + (cp-2)] = v;
        else              n1o[dst*96 + (16+u)*3 + (cp-5)] = v;
    }
}

// ---------------- Kernel E1: final per-node combine (r17-verified)
__global__ __launch_bounds__(256) void k_final_part(
    const float* __restrict__ n0p, const float* __restrict__ n1p,
    const float* __restrict__ scv, const float* __restrict__ lin2b,
    const float* __restrict__ alpha2_w, float* __restrict__ fpart)
{
    __shared__ float sred[4][3];
    const int tid = threadIdx.x;
    const int gid = blockIdx.x * 256 + tid;   // 16 blocks x 256
    const int n = gid >> 2;
    const int q = gid & 3;
    const int hsel = q >> 1, uh = (q & 1) << 4;
    const float* n0b = n0p + hsel*32768;
    const float* n1b = n1p + hsel*98304;
    float ov0 = 0.f, ov1 = 0.f, ov2 = 0.f, al = 0.f;
#pragma unroll
    for (int uu = 0; uu < 16; uu++){
        int u = uh + uu;
        float w = lin2b[u];
        ov0 += n1b[n*96 + u*3 + 0] * w;
        ov1 += n1b[n*96 + u*3 + 1] * w;
        ov2 += n1b[n*96 + u*3 + 2] * w;
        al  += n0b[n*32 + u] * alpha2_w[u];
    }
    ov0 += __shfl_xor(ov0, 1); ov0 += __shfl_xor(ov0, 2);
    ov1 += __shfl_xor(ov1, 1); ov1 += __shfl_xor(ov1, 2);
    ov2 += __shfl_xor(ov2, 1); ov2 += __shfl_xor(ov2, 2);
    al  += __shfl_xor(al , 1); al  += __shfl_xor(al , 2);
    float acc0 = 0.f, acc1 = 0.f, acc2 = 0.f;
    if (q == 0){
        al *= INV_S32_;
        acc0 = scv[n*3+0] + al * ov0 * INV_S32_;
        acc1 = scv[n*3+1] + al * ov1 * INV_S32_;
        acc2 = scv[n*3+2] + al * ov2 * INV_S32_;
    }
#pragma unroll
    for (int off = 32; off > 0; off >>= 1){
        acc0 += __shfl_down(acc0, off);
        acc1 += __shfl_down(acc1, off);
        acc2 += __shfl_down(acc2, off);
    }
    const int wv = tid >> 6, lane = tid & 63;
    if (lane == 0){ sred[wv][0] = acc0; sred[wv][1] = acc1; sred[wv][2] = acc2; }
    __syncthreads();
    if (tid == 0){
        fpart[blockIdx.x*3 + 0] = sred[0][0] + sred[1][0] + sred[2][0] + sred[3][0];
        fpart[blockIdx.x*3 + 1] = sred[0][1] + sred[1][1] + sred[2][1] + sred[3][1];
        fpart[blockIdx.x*3 + 2] = sred[0][2] + sred[1][2] + sred[2][2] + sred[3][2];
    }
}

// ---------------- Kernel E2: finish
__global__ __launch_bounds__(64) void k_final2(
    const float* __restrict__ fpart, float* __restrict__ out)
{
    const int l = threadIdx.x;
    float v0 = (l < 16) ? fpart[l*3 + 0] : 0.f;
    float v1 = (l < 16) ? fpart[l*3 + 1] : 0.f;
    float v2 = (l < 16) ? fpart[l*3 + 2] : 0.f;
#pragma unroll
    for (int off = 8; off > 0; off >>= 1){
        v0 += __shfl_down(v0, off);
        v1 += __shfl_down(v1, off);
        v2 += __shfl_down(v2, off);
    }
    if (l == 0){
        out[0] = v0 * (1.0f/32.0f);   // 1/sqrt(1024)
        out[1] = v1 * (1.0f/32.0f);
        out[2] = v2 * (1.0f/32.0f);
    }
}

extern "C" void kernel_launch(void* const* d_in, const int* in_sizes, int n_in,
                              void* d_out, int out_size, void* d_ws, size_t ws_size,
                              hipStream_t stream)
{
    const float* pos      = (const float*)d_in[0];
    const float* x        = (const float*)d_in[1];
    // d_in[2], d_in[3]: edge_src/edge_dst — dense all-pairs graph, enumerated directly
    const float* sc1_w    = (const float*)d_in[4];
    const float* lin1a_w  = (const float*)d_in[5];
    const float* fc1_w1   = (const float*)d_in[6];
    const float* fc1_w2   = (const float*)d_in[7];
    const float* lin2a0   = (const float*)d_in[8];
    const float* lin2a1   = (const float*)d_in[9];
    const float* alpha1_w = (const float*)d_in[10];
    const float* sc2_w    = (const float*)d_in[11];
    const float* lin1b0   = (const float*)d_in[12];
    const float* lin1b1   = (const float*)d_in[13];
    const float* fc2_w1   = (const float*)d_in[14];
    const float* fc2_w2   = (const float*)d_in[15];
    const float* lin2b    = (const float*)d_in[16];
    const float* alpha2_w = (const float*)d_in[17];

    float* ws    = (float*)d_ws;
    float* sc    = ws;               // 32768
    float* xl    = sc    + 32768;    // 8192
    float* m0p   = xl    + 8192;     // 2 x 8192
    float* m1p   = m0p   + 16384;    // 2 x 24576
    float* a1np  = m1p   + 49152;    // 65536
    float* scv   = a1np  + 65536;    // 3072
    float* n1p   = scv   + 3072;     // 2 x 98304
    float* fpart = n1p   + 196608;   // 48
    float* tab1  = fpart + 48;       // 2048*16 = 32768
    float* tab2  = tab1  + 32768;    // 2048*64 = 131072
    float* h1    = tab2  + 131072;   // 2048*100 = 204800
    float* h2    = h1    + 204800;   // 2048*100 = 204800
    float* n0p   = m0p;              // alias m0p+m1p (dead after node_mid)

    k_tab_h<<<NPTS, 256, 0, stream>>>(fc1_w1, fc2_w1, h1, h2);
    k_tab_out<<<640, 256, 0, stream>>>(h1, h2, fc1_w2, fc2_w2, tab1, tab2);
    k_node_pre<<<16, 256, 0, stream>>>(x, sc1_w, lin1a_w, sc, xl);
    k_edge1_tab<<<2*NND, 256, 0, stream>>>(pos, xl, tab1, m0p, m1p);
    k_node_mid<<<64, 256, 0, stream>>>(m0p, m1p, sc, lin2a0, lin2a1, alpha1_w, sc2_w,
                                       lin1b0, lin1b1, a1np, scv);
    k_edge2_tab<<<2*NND, 256, 0, stream>>>(pos, a1np, tab2, n0p, n1p);
    k_final_part<<<16, 256, 0, stream>>>(n0p, n1p, scv, lin2b, alpha2_w, fpart);
    k_final2<<<1, 64, 0, stream>>>(fpart, (float*)d_out);
}

// Round 19
// 84.446 us; speedup vs baseline: 1.9916x; 1.0694x over previous
//
#include <hip/hip_runtime.h>
#include <math.h>

#define NND 1024
#define NPTS 4096
#define R_MAX 12.0f
#define DELTA_     (R_MAX / (NPTS - 1))
#define INV_DELTA_ ((NPTS - 1) / R_MAX)

#define STEP_     (5.0f/9.0f)
#define INV_STEP_ 1.8f
#define SQ3_      1.73205080756887729f
#define INV_SQ3_  0.57735026918962576f
#define INV_NN_   0.03126527053f      /* 1/sqrt(1023) */
#define INV_S8_   0.35355339059327373f
#define INV_S32_  0.17677669529663687f
#define LOG2E_    1.44269504088896341f

typedef float f32x4 __attribute__((ext_vector_type(4)));

__device__ __forceinline__ float fast_rcp(float x){ return __builtin_amdgcn_rcpf(x); }
__device__ __forceinline__ float silu_f(float t){
    return t * fast_rcp(1.0f + __builtin_amdgcn_exp2f(t * (-LOG2E_)));
}
__device__ __forceinline__ float sigm_f(float t){
    return fast_rcp(1.0f + __builtin_amdgcn_exp2f(t * (-LOG2E_)));
}

// ---------------- Kernel T: radial tables, fused (H staged in LDS per block).
// T(r)[u] = (silu(emb@W1) @ W2) * 0.1. T[NPTS-1] (r=12) is EXACTLY 0 (emb
// underflow). blocks 0..NPTS/4-1: tab2 (4 points x 64 u); then NPTS/16 blocks:
// tab1 (16 points x 16 u). Nearest-neighbor lookup downstream (no lerp):
// err ~ w'*delta/2 ~ 1e-2, same magnitude as the bf16-MFMA version that passed.
__global__ __launch_bounds__(256) void k_tab(
    const float* __restrict__ fc1_w1, const float* __restrict__ fc1_w2,
    const float* __restrict__ fc2_w1, const float* __restrict__ fc2_w2,
    float* __restrict__ tab1, float* __restrict__ tab2)
{
    __shared__ float hs[16][104];
    const int b   = blockIdx.x;
    const int tid = threadIdx.x;
    if (b < NPTS/4){
        const int pl = tid >> 6, lane = tid & 63;
        const int p  = b*4 + pl;
        const float r = (float)p * DELTA_;
        float emb[10];
#pragma unroll
        for (int k = 0; k < 10; k++){
            float d = (r - (float)k * STEP_) * INV_STEP_;
            emb[k] = __builtin_amdgcn_exp2f((d*d) * (-LOG2E_));
        }
        for (int j = lane; j < 100; j += 64){
            float t = 0.f;
#pragma unroll
            for (int k = 0; k < 10; k++) t += emb[k] * fc2_w1[k*100 + j];
            hs[pl][j] = silu_f(t);
        }
        __syncthreads();
        float acc = 0.f;
        for (int j = 0; j < 100; j++) acc += hs[pl][j] * fc2_w2[j*64 + lane];
        tab2[p*64 + lane] = acc * 0.1f;
    } else {
        const int bb = b - NPTS/4;
        const int pl = tid >> 4, lg = tid & 15;
        const int p  = bb*16 + pl;
        const float r = (float)p * DELTA_;
        float emb[10];
#pragma unroll
        for (int k = 0; k < 10; k++){
            float d = (r - (float)k * STEP_) * INV_STEP_;
            emb[k] = __builtin_amdgcn_exp2f((d*d) * (-LOG2E_));
        }
        for (int j = lg; j < 100; j += 16){
            float t = 0.f;
#pragma unroll
            for (int k = 0; k < 10; k++) t += emb[k] * fc1_w1[k*100 + j];
            hs[pl][j] = silu_f(t);
        }
        __syncthreads();
        float acc = 0.f;
        for (int j = 0; j < 100; j++) acc += hs[pl][j] * fc1_w2[j*16 + lg];
        tab1[p*16 + lg] = acc * 0.1f;
    }
}

// nearest index: valid -> round(r/delta) clamped; invalid -> last entry (w = 0)
__device__ __forceinline__ int tab_nidx(float r, bool valid){
    float fi = valid ? (r * INV_DELTA_ + 0.5f) : (float)(NPTS - 1);
    int i0 = (int)fi;
    return (i0 > NPTS - 1) ? (NPTS - 1) : i0;
}

// ---------------- Kernel A: node pre-GEMMs (r17-verified)
__global__ __launch_bounds__(256) void k_node_pre(
    const float* __restrict__ x, const float* __restrict__ sc1_w,
    const float* __restrict__ lin1a_w, float* __restrict__ sc, float* __restrict__ xl)
{
    const int gid = blockIdx.x * 256 + threadIdx.x;
    const int n = gid >> 2, q = gid & 3;
    float xi[8];
#pragma unroll
    for (int i = 0; i < 8; i++) xi[i] = x[n*8 + i];
#pragma unroll
    for (int kk = 0; kk < 8; kk++){
        int k = q*8 + kk;
        float a = 0.f;
#pragma unroll
        for (int i = 0; i < 8; i++) a += xi[i] * sc1_w[i*32 + k];
        sc[n*32 + k] = a * INV_S8_;
    }
    if (q == 0){
#pragma unroll
        for (int k = 0; k < 8; k++){
            float a = 0.f;
#pragma unroll
            for (int i = 0; i < 8; i++) a += xi[i] * lin1a_w[i*8 + k];
            xl[n*8 + k] = a * INV_S8_;
        }
    }
}

// ---------------- Kernel B: edge pass 1 via table, nearest lookup
__global__ __launch_bounds__(256) void k_edge1_tab(
    const float* __restrict__ pos, const float* __restrict__ xl,
    const float* __restrict__ tab1, float* __restrict__ m0p, float* __restrict__ m1p)
{
    __shared__ float sred[4][32];
    const int tid  = threadIdx.x;
    const int dst  = blockIdx.x >> 1;
    const int half = blockIdx.x & 1;
    const float qx = pos[dst*3+0], qy = pos[dst*3+1], qz = pos[dst*3+2];
    float acc[32];
#pragma unroll
    for (int k = 0; k < 32; k++) acc[k] = 0.f;

#pragma unroll
    for (int it = 0; it < 2; ++it){
        const int src = half*512 + it*256 + tid;
        float dx = pos[src*3+0]-qx, dy = pos[src*3+1]-qy, dz = pos[src*3+2]-qz;
        float r2 = dx*dx + dy*dy + dz*dz;
        bool valid = (src != dst);
        float rinv = valid ? __builtin_amdgcn_rsqf(r2) : 0.f;
        float r    = r2 * rinv;
        float sf = SQ3_ * rinv;
        float y1x = dx*sf, y1y = dy*sf, y1z = dz*sf;
        const int i0 = tab_nidx(r, valid);
        const float* t0 = &tab1[i0*16];
        f32x4 w0 = *(const f32x4*)(t0     );
        f32x4 w1 = *(const f32x4*)(t0 +  4);
        f32x4 w2v= *(const f32x4*)(t0 +  8);
        f32x4 w3 = *(const f32x4*)(t0 + 12);
        float w[16] = {w0[0],w0[1],w0[2],w0[3], w1[0],w1[1],w1[2],w1[3],
                       w2v[0],w2v[1],w2v[2],w2v[3], w3[0],w3[1],w3[2],w3[3]};
        f32x4 xa = *(const f32x4*)&xl[src*8];
        f32x4 xb = *(const f32x4*)&xl[src*8+4];
        float xe[8] = {xa[0],xa[1],xa[2],xa[3], xb[0],xb[1],xb[2],xb[3]};
#pragma unroll
        for (int u = 0; u < 8; u++){
            acc[u] += w[u] * xe[u];           // 0.1 folded into table
            float qv = w[8+u] * xe[u];
            acc[8 + u*3 + 0] += qv*y1x;
            acc[8 + u*3 + 1] += qv*y1y;
            acc[8 + u*3 + 2] += qv*y1z;
        }
    }
#pragma unroll
    for (int off = 32; off > 0; off >>= 1){
#pragma unroll
        for (int k = 0; k < 32; k++) acc[k] += __shfl_down(acc[k], off);
    }
    const int wv = tid >> 6, lane = tid & 63;
    if (lane == 0){
#pragma unroll
        for (int k = 0; k < 32; k++) sred[wv][k] = acc[k];
    }
    __syncthreads();
    if (tid < 32){
        float v = (sred[0][tid] + sred[1][tid]) + (sred[2][tid] + sred[3][tid]);
        v *= INV_NN_;
        float* m0o = m0p + half*8192;
        float* m1o = m1p + half*24576;
        if (tid < 8) m0o[dst*8 + tid] = v;
        else         m1o[dst*24 + (tid - 8)] = v;
    }
}

// ---------------- Kernel C: node middle (r17-verified)
__global__ __launch_bounds__(256) void k_node_mid(
    const float* __restrict__ m0p, const float* __restrict__ m1p,
    const float* __restrict__ sc,
    const float* __restrict__ lin2a0, const float* __restrict__ lin2a1,
    const float* __restrict__ alpha1_w, const float* __restrict__ sc2_w,
    const float* __restrict__ lin1b0, const float* __restrict__ lin1b1,
    float* __restrict__ a1np, float* __restrict__ scv)
{
    const int gid = blockIdx.x * 256 + threadIdx.x;   // 64 blocks
    const int n  = gid >> 4;
    const int vo = gid & 15;
    float fm0[8];
#pragma unroll
    for (int u = 0; u < 8; u++) fm0[u] = m0p[n*8 + u] + m0p[8192 + n*8 + u];
    float alpha = 0.f;
#pragma unroll
    for (int u = 0; u < 8; u++) alpha += fm0[u] * alpha1_w[u];
    alpha *= INV_S8_;

    float x0[16], gate[16];
#pragma unroll
    for (int k = 0; k < 32; k++){
        float o = 0.f;
#pragma unroll
        for (int u = 0; u < 8; u++) o += fm0[u] * lin2a0[u*32 + k];
        float sv = sc[n*32 + k] + alpha * (o * INV_S8_);
        if (k < 16) x0[k] = silu_f(sv);
        else        gate[k - 16] = sigm_f(sv);
    }
    float fm1[8][3];
#pragma unroll
    for (int u = 0; u < 8; u++)
#pragma unroll
        for (int c = 0; c < 3; c++)
            fm1[u][c] = m1p[n*24 + u*3 + c] + m1p[24576 + n*24 + u*3 + c];

    float x1[16][3];
#pragma unroll
    for (int v = 0; v < 16; v++){
        float o0 = 0.f, o1 = 0.f, o2 = 0.f;
#pragma unroll
        for (int u = 0; u < 8; u++){
            float wv = lin2a1[u*16 + v];
            o0 += fm1[u][0] * wv; o1 += fm1[u][1] * wv; o2 += fm1[u][2] * wv;
        }
        x1[v][0] = o0 * INV_S8_ * gate[v];
        x1[v][1] = o1 * INV_S8_ * gate[v];
        x1[v][2] = o2 * INV_S8_ * gate[v];
    }
    float a = 0.f, b0 = 0.f, b1 = 0.f, b2 = 0.f;
#pragma unroll
    for (int u = 0; u < 16; u++){
        a += x0[u] * lin1b0[u*16 + vo];
        float wv = lin1b1[u*16 + vo];
        b0 += x1[u][0]*wv; b1 += x1[u][1]*wv; b2 += x1[u][2]*wv;
    }
    a1np[n*64 + vo*4 + 0] = b0 * 0.25f;
    a1np[n*64 + vo*4 + 1] = b1 * 0.25f;
    a1np[n*64 + vo*4 + 2] = b2 * 0.25f;
    a1np[n*64 + vo*4 + 3] = a  * 0.25f;   // a0 in .w
    if (vo == 0){
        float s0 = 0.f, s1 = 0.f, s2 = 0.f;
#pragma unroll
        for (int u = 0; u < 16; u++){
            float wv = sc2_w[u];
            s0 += x1[u][0]*wv; s1 += x1[u][1]*wv; s2 += x1[u][2]*wv;
        }
        scv[n*3+0] = s0 * 0.25f; scv[n*3+1] = s1 * 0.25f; scv[n*3+2] = s2 * 0.25f;
    }
}

// ---------------- Kernel D: edge pass 2 via table, nearest lookup
__global__ __launch_bounds__(256) void k_edge2_tab(
    const float* __restrict__ pos, const float* __restrict__ a1np,
    const float* __restrict__ tab2, float* __restrict__ n0p, float* __restrict__ n1p)
{
    __shared__ float sred[4][4][32];
    const int tid  = threadIdx.x;
    const int q    = tid & 3;
    const int slot = tid >> 2;
    const int dst  = blockIdx.x >> 1;
    const int half = blockIdx.x & 1;
    const float qx = pos[dst*3+0], qy = pos[dst*3+1], qz = pos[dst*3+2];

    float acc[4][8];
#pragma unroll
    for (int a = 0; a < 4; a++)
#pragma unroll
        for (int b = 0; b < 8; b++) acc[a][b] = 0.f;

#pragma unroll 2
    for (int it = 0; it < 8; ++it){
        const int src = half*512 + it*64 + slot;
        float dx = pos[src*3+0]-qx, dy = pos[src*3+1]-qy, dz = pos[src*3+2]-qz;
        float r2 = dx*dx + dy*dy + dz*dz;
        bool valid = (src != dst);
        float rinv = valid ? __builtin_amdgcn_rsqf(r2) : 0.f;
        float r    = r2 * rinv;
        float sf = SQ3_ * rinv;
        float y1x = dx*sf, y1y = dy*sf, y1z = dz*sf;
        const int i0 = tab_nidx(r, valid);
        const float* t0 = &tab2[i0*64 + q*4];
        f32x4 wav = *(const f32x4*)(t0     );
        f32x4 wbv = *(const f32x4*)(t0 + 16);
        f32x4 wcv = *(const f32x4*)(t0 + 32);
        f32x4 wdv = *(const f32x4*)(t0 + 48);
        f32x4 av0 = *(const f32x4*)&a1np[src*64 + (q*4+0)*4];
        f32x4 av1 = *(const f32x4*)&a1np[src*64 + (q*4+1)*4];
        f32x4 av2 = *(const f32x4*)&a1np[src*64 + (q*4+2)*4];
        f32x4 av3 = *(const f32x4*)&a1np[src*64 + (q*4+3)*4];
#define EPI(uu, av) { \
        float A = wav[uu], B = wbv[uu], C = wcv[uu], D = wdv[uu]; \
        acc[uu][0] += A * av[3]; \
        float dv = av[0]*y1x + av[1]*y1y + av[2]*y1z; \
        acc[uu][1] += D * dv * INV_SQ3_; \
        float t2 = B * av[3]; \
        acc[uu][2] += t2*y1x; acc[uu][3] += t2*y1y; acc[uu][4] += t2*y1z; \
        acc[uu][5] += C*av[0]; acc[uu][6] += C*av[1]; acc[uu][7] += C*av[2]; }
        EPI(0, av0) EPI(1, av1) EPI(2, av2) EPI(3, av3)
#undef EPI
    }
#pragma unroll
    for (int off = 4; off <= 32; off <<= 1)
#pragma unroll
        for (int a = 0; a < 4; a++)
#pragma unroll
            for (int b = 0; b < 8; b++) acc[a][b] += __shfl_xor(acc[a][b], off);
    const int wv = tid >> 6, lane = tid & 63;
    if (lane < 4){
#pragma unroll
        for (int a = 0; a < 4; a++)
#pragma unroll
            for (int b = 0; b < 8; b++) sred[wv][lane][a*8 + b] = acc[a][b];
    }
    __syncthreads();
    if (tid < 128){
        int q2 = tid >> 5, k = tid & 31;
        float v = (sred[0][q2][k] + sred[1][q2][k]) + (sred[2][q2][k] + sred[3][q2][k]);
        v *= INV_NN_;
        int uu = k >> 3, cp = k & 7;
        int u = q2*4 + uu;
        float* n0o = n0p + half*32768;
        float* n1o = n1p + half*98304;
        if      (cp == 0) n0o[dst*32 + u] = v;
        else if (cp == 1) n0o[dst*32 + 16 + u] = v;
        else if (cp < 5)  n1o[dst*96 + u*3 + (cp-2)] = v;
        else              n1o[dst*96 + (16+u)*3 + (cp-5)] = v;
    }
}

// ---------------- Kernel E1: final per-node combine (r17-verified)
__global__ __launch_bounds__(256) void k_final_part(
    const float* __restrict__ n0p, const float* __restrict__ n1p,
    const float* __restrict__ scv, const float* __restrict__ lin2b,
    const float* __restrict__ alpha2_w, float* __restrict__ fpart)
{
    __shared__ float sred[4][3];
    const int tid = threadIdx.x;
    const int gid = blockIdx.x * 256 + tid;   // 16 blocks x 256
    const int n = gid >> 2;
    const int q = gid & 3;
    const int hsel = q >> 1, uh = (q & 1) << 4;
    const float* n0b = n0p + hsel*32768;
    const float* n1b = n1p + hsel*98304;
    float ov0 = 0.f, ov1 = 0.f, ov2 = 0.f, al = 0.f;
#pragma unroll
    for (int uu = 0; uu < 16; uu++){
        int u = uh + uu;
        float w = lin2b[u];
        ov0 += n1b[n*96 + u*3 + 0] * w;
        ov1 += n1b[n*96 + u*3 + 1] * w;
        ov2 += n1b[n*96 + u*3 + 2] * w;
        al  += n0b[n*32 + u] * alpha2_w[u];
    }
    ov0 += __shfl_xor(ov0, 1); ov0 += __shfl_xor(ov0, 2);
    ov1 += __shfl_xor(ov1, 1); ov1 += __shfl_xor(ov1, 2);
    ov2 += __shfl_xor(ov2, 1); ov2 += __shfl_xor(ov2, 2);
    al  += __shfl_xor(al , 1); al  += __shfl_xor(al , 2);
    float acc0 = 0.f, acc1 = 0.f, acc2 = 0.f;
    if (q == 0){
        al *= INV_S32_;
        acc0 = scv[n*3+0] + al * ov0 * INV_S32_;
        acc1 = scv[n*3+1] + al * ov1 * INV_S32_;
        acc2 = scv[n*3+2] + al * ov2 * INV_S32_;
    }
#pragma unroll
    for (int off = 32; off > 0; off >>= 1){
        acc0 += __shfl_down(acc0, off);
        acc1 += __shfl_down(acc1, off);
        acc2 += __shfl_down(acc2, off);
    }
    const int wv = tid >> 6, lane = tid & 63;
    if (lane == 0){ sred[wv][0] = acc0; sred[wv][1] = acc1; sred[wv][2] = acc2; }
    __syncthreads();
    if (tid == 0){
        fpart[blockIdx.x*3 + 0] = sred[0][0] + sred[1][0] + sred[2][0] + sred[3][0];
        fpart[blockIdx.x*3 + 1] = sred[0][1] + sred[1][1] + sred[2][1] + sred[3][1];
        fpart[blockIdx.x*3 + 2] = sred[0][2] + sred[1][2] + sred[2][2] + sred[3][2];
    }
}

// ---------------- Kernel E2: finish
__global__ __launch_bounds__(64) void k_final2(
    const float* __restrict__ fpart, float* __restrict__ out)
{
    const int l = threadIdx.x;
    float v0 = (l < 16) ? fpart[l*3 + 0] : 0.f;
    float v1 = (l < 16) ? fpart[l*3 + 1] : 0.f;
    float v2 = (l < 16) ? fpart[l*3 + 2] : 0.f;
#pragma unroll
    for (int off = 8; off > 0; off >>= 1){
        v0 += __shfl_down(v0, off);
        v1 += __shfl_down(v1, off);
        v2 += __shfl_down(v2, off);
    }
    if (l == 0){
        out[0] = v0 * (1.0f/32.0f);   // 1/sqrt(1024)
        out[1] = v1 * (1.0f/32.0f);
        out[2] = v2 * (1.0f/32.0f);
    }
}

extern "C" void kernel_launch(void* const* d_in, const int* in_sizes, int n_in,
                              void* d_out, int out_size, void* d_ws, size_t ws_size,
                              hipStream_t stream)
{
    const float* pos      = (const float*)d_in[0];
    const float* x        = (const float*)d_in[1];
    // d_in[2], d_in[3]: edge_src/edge_dst — dense all-pairs graph, enumerated directly
    const float* sc1_w    = (const float*)d_in[4];
    const float* lin1a_w  = (const float*)d_in[5];
    const float* fc1_w1   = (const float*)d_in[6];
    const float* fc1_w2   = (const float*)d_in[7];
    const float* lin2a0   = (const float*)d_in[8];
    const float* lin2a1   = (const float*)d_in[9];
    const float* alpha1_w = (const float*)d_in[10];
    const float* sc2_w    = (const float*)d_in[11];
    const float* lin1b0   = (const float*)d_in[12];
    const float* lin1b1   = (const float*)d_in[13];
    const float* fc2_w1   = (const float*)d_in[14];
    const float* fc2_w2   = (const float*)d_in[15];
    const float* lin2b    = (const float*)d_in[16];
    const float* alpha2_w = (const float*)d_in[17];

    float* ws    = (float*)d_ws;
    float* sc    = ws;               // 32768
    float* xl    = sc    + 32768;    // 8192
    float* m0p   = xl    + 8192;     // 2 x 8192
    float* m1p   = m0p   + 16384;    // 2 x 24576
    float* a1np  = m1p   + 49152;    // 65536
    float* scv   = a1np  + 65536;    // 3072
    float* n1p   = scv   + 3072;     // 2 x 98304
    float* fpart = n1p   + 196608;   // 48
    float* tab1  = fpart + 48;       // 4096*16 = 65536
    float* tab2  = tab1  + 65536;    // 4096*64 = 262144
    float* n0p   = m0p;              // alias m0p+m1p (dead after node_mid)

    k_tab<<<NPTS/4 + NPTS/16, 256, 0, stream>>>(fc1_w1, fc1_w2, fc2_w1, fc2_w2, tab1, tab2);
    k_node_pre<<<16, 256, 0, stream>>>(x, sc1_w, lin1a_w, sc, xl);
    k_edge1_tab<<<2*NND, 256, 0, stream>>>(pos, xl, tab1, m0p, m1p);
    k_node_mid<<<64, 256, 0, stream>>>(m0p, m1p, sc, lin2a0, lin2a1, alpha1_w, sc2_w,
                                       lin1b0, lin1b1, a1np, scv);
    k_edge2_tab<<<2*NND, 256, 0, stream>>>(pos, a1np, tab2, n0p, n1p);
    k_final_part<<<16, 256, 0, stream>>>(n0p, n1p, scv, lin2b, alpha2_w, fpart);
    k_final2<<<1, 64, 0, stream>>>(fpart, (float*)d_out);
}